// Round 6
// baseline (582.238 us; speedup 1.0000x reference)
//
#include <hip/hip_runtime.h>
#include <stdint.h>

#define NCLS 80
#define BATCH 8
#define NA 20460          // total anchors per image across 5 levels
#define TOPK 1000
#define MAXPER 100
#define CAP 8             // capped per-class NMS depth (exact fixup via flags)
#define POOL 256          // merge candidate pool (top-100 + tie slack)
#define IMG_WF 1280.0f
#define IMG_HF 768.0f
#define CLS_OFF 4096.0f
#define MAX_RATIO_ANCHOR 13.815510557964274f  // |log(1e-6)|
#define MAX_RATIO_BBOX   4.1351665567423557f  // |log(16/1000)|

// DIAGNOSTIC ROUND: per-kernel internal repetition to force kernels past the
// 41 us harness fills into rocprof's top-5. Bodies are deterministic pure
// functions of global inputs with full per-rep re-init -> bit-identical output.
#define R_SCORE  4
#define R_SELECT 4
#define R_GATHER 4
#define R_NMS1   4
#define R_CUT    16
#define R_NMS2   4
#define R_MERGE  16

// RN(a/b) > 0.5  <=>  a > b*(0.5 + 2^-25) as reals (0.5 mantissa even, tie->down).
#define K2_HALF_UP (0.5 + 0x1p-25)

__constant__ int   c_lvoff[6]  = {0, 15360, 19200, 20160, 20400, 20460};
__constant__ int   c_lvoff4[6] = {0, 3840, 4800, 5040, 5100, 5115};   // /4
__constant__ int   c_lw[5]    = {160, 80, 40, 20, 10};
__constant__ int   c_lh[5]    = {96, 48, 24, 12, 6};
__constant__ float c_ls[5]    = {8.f, 16.f, 32.f, 64.f, 128.f};

struct InPtrs {
  const float* cls[5];
  const float* bbox[5];
  const float* shp[5];
  const float* loc[5];
};

__device__ __forceinline__ float sigf(float x) { return 1.0f / (1.0f + expf(-x)); }

// ---- DPP wave64 reductions (VALU-only) ----
__device__ __forceinline__ int wave_red_sum_i32(int v) {
  int t;
  t = __builtin_amdgcn_update_dpp(0, v, 0x111, 0xf, 0xf, false); v += t;
  t = __builtin_amdgcn_update_dpp(0, v, 0x112, 0xf, 0xf, false); v += t;
  t = __builtin_amdgcn_update_dpp(0, v, 0x114, 0xf, 0xf, false); v += t;
  t = __builtin_amdgcn_update_dpp(0, v, 0x118, 0xf, 0xf, false); v += t;
  t = __builtin_amdgcn_update_dpp(0, v, 0x142, 0xf, 0xf, false); v += t;
  t = __builtin_amdgcn_update_dpp(0, v, 0x143, 0xf, 0xf, false); v += t;
  return __builtin_amdgcn_readlane(v, 63);
}
__device__ __forceinline__ void wave_red_top2(unsigned m1, unsigned m2,
                                              unsigned& r1, unsigned& r2) {
#define T2STEP(ctrl) { \
    unsigned o1 = (unsigned)__builtin_amdgcn_update_dpp(0, (int)m1, ctrl, 0xf, 0xf, false); \
    unsigned o2 = (unsigned)__builtin_amdgcn_update_dpp(0, (int)m2, ctrl, 0xf, 0xf, false); \
    unsigned tm = min(m1, o1); \
    m1 = max(m1, o1); \
    m2 = max(tm, max(m2, o2)); }
  T2STEP(0x111) T2STEP(0x112) T2STEP(0x114) T2STEP(0x118) T2STEP(0x142) T2STEP(0x143)
#undef T2STEP
  r1 = (unsigned)__builtin_amdgcn_readlane((int)m1, 63);
  r2 = (unsigned)__builtin_amdgcn_readlane((int)m2, 63);
}

// ---------------- K1: per-anchor max score -> w22 comparable keys ----------------
// NO global histogram (round-5 lesson: clustered scores -> same-address atomic
// serialization, +45 us). w = float bits & 0x3FFFFF (0 for dead), monotone.
__global__ __launch_bounds__(256) void k_score(InPtrs P, unsigned* wkeys, int reps) {
  int gid = blockIdx.x * 256 + threadIdx.x;
  if (gid >= BATCH * (NA / 4)) return;
  int b = gid / (NA / 4);
  int q = gid - b * (NA / 4);
  int l = 0;
  while (q >= c_lvoff4[l + 1]) ++l;
  int hw = c_lh[l] * c_lw[l];
  int sp = (q - c_lvoff4[l]) * 4;
  for (int rep = 0; rep < reps; ++rep) {
    const float4* cls = (const float4*)(P.cls[l] + (size_t)(b * NCLS) * hw + sp);
    int s4 = hw >> 2;
    float4 m = cls[0];
    for (int c = 1; c < NCLS; ++c) {
      float4 v = cls[(size_t)c * s4];
      m.x = fmaxf(m.x, v.x); m.y = fmaxf(m.y, v.y);
      m.z = fmaxf(m.z, v.z); m.w = fmaxf(m.w, v.w);
    }
    float4 lo = *(const float4*)(P.loc[l] + (size_t)b * hw + sp);
    float4 r;
    r.x = (sigf(lo.x) >= 0.01f) ? sigf(sigf(m.x)) : 0.0f;
    r.y = (sigf(lo.y) >= 0.01f) ? sigf(sigf(m.y)) : 0.0f;
    r.z = (sigf(lo.z) >= 0.01f) ? sigf(sigf(m.z)) : 0.0f;
    r.w = (sigf(lo.w) >= 0.01f) ? sigf(sigf(m.w)) : 0.0f;
    uint4 wq;
    wq.x = __float_as_uint(r.x) & 0x3FFFFFu;
    wq.y = __float_as_uint(r.y) & 0x3FFFFFu;
    wq.z = __float_as_uint(r.z) & 0x3FFFFFu;
    wq.w = __float_as_uint(r.w) & 0x3FFFFFu;
    ((uint4*)wkeys)[(size_t)b * (NA / 4) + q] = wq;
  }
}

// ---------------- K2: exact top-1000 per batch (LDS two-level histogram) --------
__global__ __launch_bounds__(1024) void k_select(const unsigned* wkeys, int* sel, int reps) {
  int b = blockIdx.x;
  int tid = threadIdx.x;
  int wv = tid >> 6;
  int lane = tid & 63;
  __shared__ unsigned s_h[2048];
  __shared__ int s_wtot[16];
  __shared__ int s_res[2];
  __shared__ unsigned long long s_A[1024];
  __shared__ unsigned long long s_B[1024];
  const int NAq = NA / 4;

  for (int rep = 0; rep < reps; ++rep) {
    unsigned w[20];
    #pragma unroll
    for (int k = 0; k < 5; ++k) {
      int q = tid * 5 + k;
      uint4 u = (q < NAq) ? ((const uint4*)wkeys)[(size_t)b * NAq + q]
                          : make_uint4(0u, 0u, 0u, 0u);
      w[k * 4 + 0] = u.x; w[k * 4 + 1] = u.y; w[k * 4 + 2] = u.z; w[k * 4 + 3] = u.w;
    }
    int lim = NA - tid * 20;
    lim = (lim < 0) ? 0 : ((lim > 20) ? 20 : lim);

    s_h[tid] = 0u; s_h[tid + 1024] = 0u;
    __syncthreads();

    auto scanFind = [&](int target) {
      int b0 = 2047 - 2 * tid;
      int h0 = (int)s_h[b0];
      int h1 = (int)s_h[b0 - 1];
      int pair = h0 + h1;
      int incl = pair;
      #pragma unroll
      for (int o = 1; o < 64; o <<= 1) {
        int uu = __shfl_up(incl, o, 64);
        if (lane >= o) incl += uu;
      }
      if (lane == 63) s_wtot[wv] = incl;
      __syncthreads();
      int woff = 0;
      #pragma unroll
      for (int ww = 0; ww < 16; ++ww) woff += (ww < wv) ? s_wtot[ww] : 0;
      int excl = woff + incl - pair;
      if (excl < target && excl + h0 >= target) { s_res[0] = b0; s_res[1] = excl; }
      int e1 = excl + h0;
      if (e1 < target && e1 + h1 >= target) { s_res[0] = b0 - 1; s_res[1] = e1; }
      __syncthreads();
    };

    #pragma unroll
    for (int k = 0; k < 20; ++k) atomicAdd(&s_h[w[k] >> 11], 1u);
    __syncthreads();
    scanFind(TOPK);
    int B1 = s_res[0];
    int NGT1 = s_res[1];

    s_h[tid] = 0u; s_h[tid + 1024] = 0u;
    __syncthreads();
    #pragma unroll
    for (int k = 0; k < 20; ++k)
      if ((int)(w[k] >> 11) == B1) atomicAdd(&s_h[w[k] & 0x7FFu], 1u);
    __syncthreads();
    scanFind(TOPK - NGT1);
    unsigned V = ((unsigned)B1 << 11) | (unsigned)s_res[0];

    if (tid < 1024 - TOPK) s_A[TOPK + tid] = 0ull;

    int cgt = 0;
    #pragma unroll
    for (int k = 0; k < 20; ++k) cgt += (w[k] > V) ? 1 : 0;
    {
      int incl = cgt;
      #pragma unroll
      for (int o = 1; o < 64; o <<= 1) {
        int uu = __shfl_up(incl, o, 64);
        if (lane >= o) incl += uu;
      }
      if (lane == 63) s_wtot[wv] = incl;
      __syncthreads();
      int woff = 0, tot = 0;
      #pragma unroll
      for (int ww = 0; ww < 16; ++ww) { tot += s_wtot[ww]; woff += (ww < wv) ? s_wtot[ww] : 0; }
      int pos = woff + incl - cgt;
      #pragma unroll
      for (int k = 0; k < 20; ++k) {
        if (w[k] > V) {
          int i = tid * 20 + k;
          s_A[pos++] = ((unsigned long long)w[k] << 32) |
                       (unsigned long long)(0xFFFFFFFFu - (unsigned)i);
        }
      }
      int ngt = tot;
      int need = TOPK - ngt;
      __syncthreads();

      int ceq = 0;
      #pragma unroll
      for (int k = 0; k < 20; ++k) if (k < lim && w[k] == V) ++ceq;
      int incl2 = ceq;
      #pragma unroll
      for (int o = 1; o < 64; o <<= 1) {
        int uu = __shfl_up(incl2, o, 64);
        if (lane >= o) incl2 += uu;
      }
      if (lane == 63) s_wtot[wv] = incl2;
      __syncthreads();
      int woff2 = 0;
      #pragma unroll
      for (int ww = 0; ww < 16; ++ww) woff2 += (ww < wv) ? s_wtot[ww] : 0;
      int r = woff2 + incl2 - ceq;
      #pragma unroll
      for (int k = 0; k < 20; ++k) {
        if (k < lim && w[k] == V) {
          if (r < need) {
            int i = tid * 20 + k;
            s_A[ngt + r] = ((unsigned long long)V << 32) |
                           (unsigned long long)(0xFFFFFFFFu - (unsigned)i);
          }
          ++r;
        }
      }
    }
    __syncthreads();

    unsigned long long key = s_A[tid];
    int tog = 0;
    for (unsigned k = 2; k <= 1024; k <<= 1) {
      for (unsigned j = k >> 1; j > 0; j >>= 1) {
        unsigned long long other;
        if (j >= 64) {
          unsigned long long* cur = tog ? s_A : s_B;
          cur[tid] = key;
          __syncthreads();
          other = cur[tid ^ (int)j];
          tog ^= 1;
        } else {
          other = __shfl_xor(key, (int)j, 64);
        }
        bool takeMax = (((tid & (int)k) == 0) == ((tid & (int)j) == 0));
        unsigned long long mx = (key > other) ? key : other;
        unsigned long long mn = (key > other) ? other : key;
        key = takeMax ? mx : mn;
      }
    }
    if (tid < TOPK) {
      sel[b * TOPK + tid] = (int)(0xFFFFFFFFu - (unsigned)(key & 0xFFFFFFFFull));
    }
    __syncthreads();   // fence bitonic LDS reads vs next rep's writes
  }
}

// ---------------- K3: decode boxes + 80 class scores, one WAVE per row ----------
__global__ __launch_bounds__(256) void k_gather(InPtrs P, const int* sel, float* boxes,
                                                float* sv, int reps) {
  int wvi = threadIdx.x >> 6;
  int lane = threadIdx.x & 63;
  int wid = blockIdx.x * 4 + wvi;
  int b = wid / TOPK;
  int r = wid - b * TOPK;
  __shared__ float s_sc[4][NCLS];

  for (int rep = 0; rep < reps; ++rep) {
    int a = sel[b * TOPK + r];
    int l = 0;
    while (a >= c_lvoff[l + 1]) ++l;
    int within = a - c_lvoff[l];
    int W = c_lw[l], H = c_lh[l];
    int y = within / W, x = within - y * W;
    int hw = H * W;
    int sp = within;
    float stride = c_ls[l];
    float px = (float)x * stride;
    float py = (float)y * stride;
    float pw = 4.0f * stride;

    const float* shp = P.shp[l];
    float dws = shp[(b * 2 + 0) * hw + sp];
    float dhs = shp[(b * 2 + 1) * hw + sp];
    dws = fminf(fmaxf(dws, -MAX_RATIO_ANCHOR), MAX_RATIO_ANCHOR);
    dhs = fminf(fmaxf(dhs, -MAX_RATIO_ANCHOR), MAX_RATIO_ANCHOR);
    float gw = pw * expf(dws);
    float gh = pw * expf(dhs);
    float ax1 = px - 0.5f * gw, ax2 = px + 0.5f * gw;
    float ay1 = py - 0.5f * gh, ay2 = py + 0.5f * gh;

    const float* bb = P.bbox[l];
    float dx = bb[(b * 4 + 0) * hw + sp];
    float dy = bb[(b * 4 + 1) * hw + sp];
    float dw = bb[(b * 4 + 2) * hw + sp];
    float dh = bb[(b * 4 + 3) * hw + sp];
    dw = fminf(fmaxf(dw, -MAX_RATIO_BBOX), MAX_RATIO_BBOX);
    dh = fminf(fmaxf(dh, -MAX_RATIO_BBOX), MAX_RATIO_BBOX);
    float px2 = (ax1 + ax2) * 0.5f, py2 = (ay1 + ay2) * 0.5f;
    float pw2 = ax2 - ax1, ph2 = ay2 - ay1;
    float gx = px2 + pw2 * dx, gy = py2 + ph2 * dy;
    float gw2 = pw2 * expf(dw), gh2 = ph2 * expf(dh);
    float x1 = fminf(fmaxf(gx - 0.5f * gw2, 0.0f), IMG_WF);
    float x2 = fminf(fmaxf(gx + 0.5f * gw2, 0.0f), IMG_WF);
    float y1 = fminf(fmaxf(gy - 0.5f * gh2, 0.0f), IMG_HF);
    float y2 = fminf(fmaxf(gy + 0.5f * gh2, 0.0f), IMG_HF);
    if (lane == 0) {
      float4 st; st.x = x1; st.y = y1; st.z = x2; st.w = y2;
      ((float4*)boxes)[b * TOPK + r] = st;
    }

    const float* cls = P.cls[l];
    float sl = sigf(P.loc[l][b * hw + sp]);
    bool mask = (sl >= 0.01f);
    int base = (b * NCLS) * hw + sp;
    for (int c = lane; c < NCLS; c += 64) {
      float vv = 0.0f;
      if (mask) {
        float s2 = sigf(sigf(cls[base + c * hw]));
        vv = (s2 > 0.05f) ? s2 : 0.0f;
      }
      s_sc[wvi][c] = vv;
    }
    __syncthreads();
    int t = threadIdx.x;
    if (t < NCLS) {
      int r0 = blockIdx.x * 4 - b * TOPK;
      float4 o; o.x = s_sc[0][t]; o.y = s_sc[1][t]; o.z = s_sc[2][t]; o.w = s_sc[3][t];
      *(float4*)(sv + ((size_t)(b * NCLS + t) * TOPK + r0)) = o;
    }
    __syncthreads();   // fence s_sc reads vs next rep's writes
  }
}

// ---------------- K4: per-(batch,class) greedy NMS ----------------
__global__ __launch_bounds__(256) void k_nms(const float* boxes, const float* sv,
                                             float* keptScore, int* keptRow, int* kc,
                                             const int* flags, const int* gbits, int cap,
                                             int reps) {
  int bc = blockIdx.x;
  int b = bc / NCLS;
  int c = bc - b * NCLS;
  int tid = threadIdx.x;
  int wv = tid >> 6, lane = tid & 63;

  __shared__ float4 s_box[TOPK];
  __shared__ float  s_ard[TOPK];
  __shared__ unsigned long long s_p2[2][4];

  if (flags && flags[bc] == 0) return;   // uniform early-exit (fixup pass)

  unsigned Glow = 0u;
  if (gbits) Glow = ((unsigned)gbits[b]) & 0x3FFFFFu;

  for (int rep = 0; rep < reps; ++rep) {
    float x1[4], y1[4], x2[4], y2[4], ar[4];
    unsigned key[4];
    float off = (float)c * CLS_OFF;
    const float* svc = sv + (size_t)(b * NCLS + c) * TOPK;
    #pragma unroll
    for (int j = 0; j < 4; ++j) {
      int row = j * 256 + tid;
      if (row < TOPK) {
        float4 bo = ((const float4*)boxes)[b * TOPK + row];
        float a = bo.x + off, d = bo.y + off, e = bo.z + off, f = bo.w + off;
        x1[j] = a; y1[j] = d; x2[j] = e; y2[j] = f;
        ar[j] = (e - a) * (f - d);
        unsigned bits = __float_as_uint(svc[row]);
        key[j] = ((bits & 0x3FFFFFu) << 10) | (1023u - (unsigned)row);
        float sden = ar[j] + 1e-6f;
        bool deg = !((double)ar[j] > (double)sden * K2_HALF_UP);
        float4 sb; sb.x = a; sb.y = d; sb.z = e; sb.w = f;
        s_box[row] = sb;
        s_ard[row] = __uint_as_float(__float_as_uint(ar[j]) | (deg ? 0x80000000u : 0u));
      } else {
        x1[j] = y1[j] = x2[j] = y2[j] = ar[j] = 0.0f;
        key[j] = 0u;
      }
    }
    __syncthreads();

    int kept = 0;
    bool sticky = false;
    float* ks = keptScore + (size_t)(b * NCLS + c) * MAXPER;
    int*   kr = keptRow   + (size_t)(b * NCLS + c) * MAXPER;

    for (int round = 0; round < cap; ++round) {
      int par = round & 1;
      unsigned hi1 = max(key[0], key[1]), lo1 = min(key[0], key[1]);
      unsigned hi2 = max(key[2], key[3]), lo2 = min(key[2], key[3]);
      unsigned m1 = max(hi1, hi2);
      unsigned m2 = max(min(hi1, hi2), max(lo1, lo2));
      unsigned w1, w2;
      wave_red_top2(m1, m2, w1, w2);
      if (lane == 0) s_p2[par][wv] = ((unsigned long long)w1 << 32) | w2;
      __syncthreads();
      unsigned k0 = 0u, k1 = 0u;
      #pragma unroll
      for (int w = 0; w < 4; ++w) {
        unsigned long long pp = s_p2[par][w];
        unsigned p1 = (unsigned)(pp >> 32), p2 = (unsigned)pp;
        unsigned tm = min(k0, p1);
        k0 = max(k0, p1);
        k1 = max(tm, max(k1, p2));
      }
      if (k0 < 1024u) break;
      if ((k0 >> 10) < Glow) break;
      int brow1 = 1023 - (int)(k0 & 1023u);
      float bs1 = __uint_as_float(0x3F000000u | (k0 >> 10));
      float4 bb1 = s_box[brow1];
      unsigned au1 = __float_as_uint(s_ard[brow1]);
      bool deg1 = (au1 >> 31) != 0u;
      float ba1 = __uint_as_float(au1 & 0x7FFFFFFFu);
      if (tid == 0) { ks[kept] = bs1; kr[kept] = brow1; }
      kept++;
      if (deg1) { sticky = true; break; }
      if (kept >= cap) break;
      bool live2 = (k1 >= 1024u) && ((k1 >> 10) >= Glow);
      if (!live2) break;
      bool do2 = false, deg2 = false;
      float4 bb2; float ba2 = 0.0f;
      {
        int brow2 = 1023 - (int)(k1 & 1023u);
        float bs2 = __uint_as_float(0x3F000000u | (k1 >> 10));
        bb2 = s_box[brow2];
        unsigned au2 = __float_as_uint(s_ard[brow2]);
        deg2 = (au2 >> 31) != 0u;
        ba2 = __uint_as_float(au2 & 0x7FFFFFFFu);
        float ltx = fmaxf(bb1.x, bb2.x), rbx = fminf(bb1.z, bb2.z);
        float lty = fmaxf(bb1.y, bb2.y), rby = fminf(bb1.w, bb2.w);
        float w_ = fmaxf(rbx - ltx, 0.0f), h_ = fmaxf(rby - lty, 0.0f);
        float inter = w_ * h_;
        float denom = ((ba1 + ba2) - inter) + 1e-6f;
        if (!((double)inter > (double)denom * K2_HALF_UP)) {
          do2 = true;
          if (tid == 0) { ks[kept] = bs2; kr[kept] = brow2; }
          kept++;
        }
      }
      if (do2 && deg2) { sticky = true; break; }
      #pragma unroll
      for (int j = 0; j < 4; ++j) {
        {
          float ltx = fmaxf(bb1.x, x1[j]), rbx = fminf(bb1.z, x2[j]);
          float lty = fmaxf(bb1.y, y1[j]), rby = fminf(bb1.w, y2[j]);
          float w_ = fmaxf(rbx - ltx, 0.0f), h_ = fmaxf(rby - lty, 0.0f);
          float inter = w_ * h_;
          float denom = ((ba1 + ar[j]) - inter) + 1e-6f;
          if ((double)inter > (double)denom * K2_HALF_UP) key[j] = 0u;
        }
        if (do2) {
          float ltx = fmaxf(bb2.x, x1[j]), rbx = fminf(bb2.z, x2[j]);
          float lty = fmaxf(bb2.y, y1[j]), rby = fminf(bb2.w, y2[j]);
          float w_ = fmaxf(rbx - ltx, 0.0f), h_ = fmaxf(rby - lty, 0.0f);
          float inter = w_ * h_;
          float denom = ((ba2 + ar[j]) - inter) + 1e-6f;
          if ((double)inter > (double)denom * K2_HALF_UP) key[j] = 0u;
        }
      }
      if (kept >= cap) break;
    }
    if (tid == 0) kc[b * NCLS + c] = sticky ? -kept : kept;
    __syncthreads();   // fence s_box/s_ard reads vs next rep's writes
  }
}

// ---------------- K4b: fixup decision + per-batch G ----------------
__global__ __launch_bounds__(256) void k_cut(const float* keptScore, const int* kc,
                                             int* flags, int* gbits, int reps) {
  int b = blockIdx.x;
  int tid = threadIdx.x;
  int wv = tid >> 6, lane = tid & 63;
  __shared__ int s_abs[NCLS];
  __shared__ int s_neg[NCLS];
  __shared__ unsigned s_h[2048];
  __shared__ int s_wtot[4];
  __shared__ int s_res[2];
  __shared__ int s_tot[4];

  for (int rep = 0; rep < reps; ++rep) {
    if (tid < NCLS) {
      int v = kc[b * NCLS + tid];
      s_abs[tid] = (v < 0) ? -v : v;
      s_neg[tid] = (v < 0) ? 1 : 0;
    }
    #pragma unroll
    for (int j = 0; j < 8; ++j) s_h[tid * 8 + j] = 0u;
    __syncthreads();

    unsigned vv[3] = {0u, 0u, 0u};
    #pragma unroll
    for (int t = 0; t < 3; ++t) {
      int e = tid + t * 256;
      if (e < NCLS * CAP) {
        int c = e / CAP, k = e - c * CAP;
        if (k < s_abs[c])
          vv[t] = __float_as_uint(keptScore[(size_t)b * NCLS * MAXPER + c * MAXPER + k])
                  & 0x3FFFFFu;
      }
    }
    int live = ((vv[0] != 0u) ? 1 : 0) + ((vv[1] != 0u) ? 1 : 0) + ((vv[2] != 0u) ? 1 : 0);
    live = wave_red_sum_i32(live);
    if (lane == 0) s_tot[wv] = live;
    #pragma unroll
    for (int t = 0; t < 3; ++t) if (vv[t]) atomicAdd(&s_h[vv[t] >> 11], 1u);
    __syncthreads();
    int T = s_tot[0] + s_tot[1] + s_tot[2] + s_tot[3];

    auto scanFind = [&](int target) {
      int base = 2047 - 8 * tid;
      int h[8]; int loc = 0;
      #pragma unroll
      for (int j = 0; j < 8; ++j) { h[j] = (int)s_h[base - j]; loc += h[j]; }
      int incl = loc;
      #pragma unroll
      for (int o = 1; o < 64; o <<= 1) {
        int uu = __shfl_up(incl, o, 64);
        if (lane >= o) incl += uu;
      }
      if (lane == 63) s_wtot[wv] = incl;
      __syncthreads();
      int woff = 0;
      #pragma unroll
      for (int ww = 0; ww < 4; ++ww) woff += (ww < wv) ? s_wtot[ww] : 0;
      int e = woff + incl - loc;
      #pragma unroll
      for (int j = 0; j < 8; ++j) {
        if (e < target && e + h[j] >= target) { s_res[0] = base - j; s_res[1] = e; }
        e += h[j];
      }
      __syncthreads();
    };

    unsigned G = 0u;
    if (T >= MAXPER) {
      scanFind(MAXPER);
      int B1 = s_res[0], NGT1 = s_res[1];
      #pragma unroll
      for (int j = 0; j < 8; ++j) s_h[tid * 8 + j] = 0u;
      __syncthreads();
      #pragma unroll
      for (int t = 0; t < 3; ++t)
        if (vv[t] && (int)(vv[t] >> 11) == B1) atomicAdd(&s_h[vv[t] & 0x7FFu], 1u);
      __syncthreads();
      scanFind(MAXPER - NGT1);
      G = 0x3F000000u | ((unsigned)B1 << 11) | (unsigned)s_res[0];
    }
    if (tid == 0) gbits[b] = (int)G;
    if (tid < NCLS) {
      int f = 0;
      if (s_abs[tid] == CAP && !s_neg[tid]) {
        unsigned slast = __float_as_uint(
            keptScore[(size_t)b * NCLS * MAXPER + tid * MAXPER + (CAP - 1)]);
        if (slast >= G) f = 1;
      }
      flags[b * NCLS + tid] = f;
    }
    __syncthreads();
  }
}

// ---------------- K5: sort-based merge -> top-100 ----------------
__global__ __launch_bounds__(256) void k_merge(const float* boxes, const float* keptScore,
                                               const int* keptRow, const int* kc, float* out,
                                               int reps) {
  int b = blockIdx.x;
  int tid = threadIdx.x;
  int wv = tid >> 6, lane = tid & 63;
  __shared__ int s_kc[NCLS];
  __shared__ unsigned s_h[2048];
  __shared__ int s_wtot[4];
  __shared__ int s_res[2];
  __shared__ int s_tot[4];
  __shared__ int s_pos;
  __shared__ int s_sticky;
  __shared__ int s_navail;
  __shared__ unsigned long long s_pool[POOL];
  __shared__ unsigned long long s_sorted[POOL];

  for (int rep = 0; rep < reps; ++rep) {
    for (int c = tid; c < NCLS; c += 256) s_kc[c] = kc[b * NCLS + c];
    if (tid == 0) { s_pos = 0; s_sticky = 0x7FFFFFFF; s_navail = 0; }
    for (int i = tid; i < POOL; i += 256) { s_pool[i] = 0ull; s_sorted[i] = 0ull; }
    #pragma unroll
    for (int j = 0; j < 8; ++j) s_h[tid * 8 + j] = 0u;
    __syncthreads();

    unsigned sc[32];
    #pragma unroll
    for (int s = 0; s < 32; ++s) {
      int i = tid + s * 256;
      unsigned vvv = 0u;
      if (i < NCLS * MAXPER) {
        int c = i / MAXPER, k = i - c * MAXPER;
        int kcv = s_kc[c];
        int ka = (kcv < 0) ? -kcv : kcv;
        if (k < ka)
          vvv = __float_as_uint(keptScore[(size_t)b * NCLS * MAXPER + i]) & 0x3FFFFFu;
      }
      sc[s] = vvv;
    }
    int live = 0;
    #pragma unroll
    for (int s = 0; s < 32; ++s) live += (sc[s] != 0u) ? 1 : 0;
    live = wave_red_sum_i32(live);
    if (lane == 0) s_tot[wv] = live;
    #pragma unroll
    for (int s = 0; s < 32; ++s) if (sc[s]) atomicAdd(&s_h[sc[s] >> 11], 1u);
    __syncthreads();
    int T = s_tot[0] + s_tot[1] + s_tot[2] + s_tot[3];

    auto scanFind = [&](int target) {
      int base = 2047 - 8 * tid;
      int h[8]; int loc = 0;
      #pragma unroll
      for (int j = 0; j < 8; ++j) { h[j] = (int)s_h[base - j]; loc += h[j]; }
      int incl = loc;
      #pragma unroll
      for (int o = 1; o < 64; o <<= 1) {
        int uu = __shfl_up(incl, o, 64);
        if (lane >= o) incl += uu;
      }
      if (lane == 63) s_wtot[wv] = incl;
      __syncthreads();
      int woff = 0;
      #pragma unroll
      for (int ww = 0; ww < 4; ++ww) woff += (ww < wv) ? s_wtot[ww] : 0;
      int e = woff + incl - loc;
      #pragma unroll
      for (int j = 0; j < 8; ++j) {
        if (e < target && e + h[j] >= target) { s_res[0] = base - j; s_res[1] = e; }
        e += h[j];
      }
      __syncthreads();
    };

    unsigned V = 1u;
    if (T > MAXPER) {
      scanFind(MAXPER);
      int B1 = s_res[0], NGT1 = s_res[1];
      #pragma unroll
      for (int j = 0; j < 8; ++j) s_h[tid * 8 + j] = 0u;
      __syncthreads();
      #pragma unroll
      for (int s = 0; s < 32; ++s)
        if (sc[s] && (int)(sc[s] >> 11) == B1) atomicAdd(&s_h[sc[s] & 0x7FFu], 1u);
      __syncthreads();
      scanFind(MAXPER - NGT1);
      V = ((unsigned)B1 << 11) | (unsigned)s_res[0];
    }

    #pragma unroll
    for (int s = 0; s < 32; ++s) {
      if (sc[s] >= V && sc[s] != 0u) {
        int i = tid + s * 256;
        int c = i / MAXPER, k = i - c * MAXPER;
        int kcv = s_kc[c];
        int ka = (kcv < 0) ? -kcv : kcv;
        unsigned st = (kcv < 0 && k == ka - 1) ? 1u : 0u;
        unsigned row = (unsigned)keptRow[(size_t)b * NCLS * MAXPER + i];
        unsigned flat = row * 80u + (unsigned)c;
        int p = atomicAdd(&s_pos, 1);
        if (p < POOL)
          s_pool[p] = ((unsigned long long)(0x3F000000u | sc[s]) << 32) |
                      (unsigned long long)(0x7FFFFFFFu - ((flat << 1) | st));
      }
    }
    __syncthreads();

    if (tid < POOL) {
      unsigned long long mykey = s_pool[tid];
      if (mykey != 0ull) {
        int rank = 0;
        #pragma unroll 8
        for (int s = 0; s < POOL; ++s) rank += (s_pool[s] > mykey) ? 1 : 0;
        s_sorted[rank] = mykey;
      }
    }
    __syncthreads();

    if (tid < MAXPER) {
      unsigned long long key = s_sorted[tid];
      if (key != 0ull) {
        atomicAdd(&s_navail, 1);
        if ((((unsigned)key) & 1u) == 0u) atomicMin(&s_sticky, tid);
      }
    }
    __syncthreads();
    int navail = s_navail;
    int p = s_sticky;
    int n = (p < navail) ? MAXPER : navail;

    if (tid == 0) out[b] = (float)n;
    const int OB = BATCH;
    const int OP = OB + BATCH * MAXPER * 4;
    const int OS = OP + BATCH * MAXPER;
    if (tid < MAXPER) {
      int k = tid;
      float bx0 = 0.f, bx1 = 0.f, bx2 = 0.f, bx3 = 0.f, scf = 0.f, cf = -1.0f;
      if (k < n) {
        int idx = (k > p) ? p : k;
        unsigned long long key = s_sorted[idx];
        unsigned flat = (0x7FFFFFFFu - (unsigned)key) >> 1;
        unsigned cls = flat % 80u;
        unsigned row = flat / 80u;
        float4 bo = ((const float4*)boxes)[b * TOPK + row];
        bx0 = bo.x; bx1 = bo.y; bx2 = bo.z; bx3 = bo.w;
        scf = __uint_as_float((unsigned)(key >> 32));
        cf = (float)cls;
      }
      float* po = out + OB + (size_t)(b * MAXPER + k) * 4;
      po[0] = bx0; po[1] = bx1; po[2] = bx2; po[3] = bx3;
      out[OP + b * MAXPER + k] = scf;
      out[OS + b * MAXPER + k] = cf;
    }
    __syncthreads();
  }
}

extern "C" void kernel_launch(void* const* d_in, const int* in_sizes, int n_in,
                              void* d_out, int out_size, void* d_ws, size_t ws_size,
                              hipStream_t stream) {
  InPtrs P;
  for (int l = 0; l < 5; ++l) {
    P.cls[l]  = (const float*)d_in[4 * l + 0];
    P.bbox[l] = (const float*)d_in[4 * l + 1];
    P.shp[l]  = (const float*)d_in[4 * l + 2];
    P.loc[l]  = (const float*)d_in[4 * l + 3];
  }
  unsigned* wkeys  = (unsigned*)d_ws;                       // B*NA
  int*   sel       = (int*)(wkeys + BATCH * NA);            // B*TOPK
  float* boxes     = (float*)(sel + BATCH * TOPK);          // B*TOPK*4 (16B aligned)
  float* sv        = boxes + BATCH * TOPK * 4;              // B*80*TOPK (class-major)
  float* keptScore = sv + BATCH * NCLS * TOPK;              // B*80*100
  int*   keptRow   = (int*)(keptScore + BATCH * NCLS * MAXPER);
  int*   kc        = keptRow + BATCH * NCLS * MAXPER;
  int*   flags     = kc + BATCH * NCLS;
  int*   gbits     = flags + BATCH * NCLS;
  float* out = (float*)d_out;

  k_score<<<(BATCH * (NA / 4) + 255) / 256, 256, 0, stream>>>(P, wkeys, R_SCORE);
  k_select<<<BATCH, 1024, 0, stream>>>(wkeys, sel, R_SELECT);
  k_gather<<<BATCH * TOPK / 4, 256, 0, stream>>>(P, sel, boxes, sv, R_GATHER);
  k_nms<<<BATCH * NCLS, 256, 0, stream>>>(boxes, sv, keptScore, keptRow, kc,
                                          (const int*)nullptr, (const int*)nullptr, CAP, R_NMS1);
  k_cut<<<BATCH, 256, 0, stream>>>(keptScore, kc, flags, gbits, R_CUT);
  k_nms<<<BATCH * NCLS, 256, 0, stream>>>(boxes, sv, keptScore, keptRow, kc,
                                          flags, gbits, MAXPER, R_NMS2);
  k_merge<<<BATCH, 256, 0, stream>>>(boxes, keptScore, keptRow, kc, out, R_MERGE);
}

// Round 7
// 214.047 us; speedup vs baseline: 2.7201x; 2.7201x over previous
//
#include <hip/hip_runtime.h>
#include <stdint.h>

#define NCLS 80
#define BATCH 8
#define NA 20460          // total anchors per image across 5 levels
#define TOPK 1000
#define MAXPER 100
#define CAP 8             // capped per-class NMS depth (exact fixup via flags)
#define POOL 256          // merge candidate pool (top-100 + tie slack)
#define IMG_WF 1280.0f
#define IMG_HF 768.0f
#define CLS_OFF 4096.0f
#define MAX_RATIO_ANCHOR 13.815510557964274f  // |log(1e-6)|
#define MAX_RATIO_BBOX   4.1351665567423557f  // |log(16/1000)|

// RN(a/b) > 0.5  <=>  a > b*(0.5 + 2^-25) as reals (0.5 mantissa even, tie->down).
#define K2_HALF_UP (0.5 + 0x1p-25)

// Live w22 keys (sig(sig(x)) in (0.5, 0.734375)) lie in [1, 0x3C0000); 0 = dead.
#define WLIVE_LO 1u
#define WLIVE_HI 0x3C0000u

__constant__ int   c_lvoff[6]  = {0, 15360, 19200, 20160, 20400, 20460};
__constant__ int   c_lvoff4[6] = {0, 3840, 4800, 5040, 5100, 5115};   // /4
__constant__ int   c_lw[5]    = {160, 80, 40, 20, 10};
__constant__ int   c_lh[5]    = {96, 48, 24, 12, 6};
__constant__ float c_ls[5]    = {8.f, 16.f, 32.f, 64.f, 128.f};

struct InPtrs {
  const float* cls[5];
  const float* bbox[5];
  const float* shp[5];
  const float* loc[5];
};

__device__ __forceinline__ float sigf(float x) { return 1.0f / (1.0f + expf(-x)); }

// ---- DPP wave64 reductions (VALU-only) ----
__device__ __forceinline__ int wave_red_sum_i32(int v) {
  int t;
  t = __builtin_amdgcn_update_dpp(0, v, 0x111, 0xf, 0xf, false); v += t;
  t = __builtin_amdgcn_update_dpp(0, v, 0x112, 0xf, 0xf, false); v += t;
  t = __builtin_amdgcn_update_dpp(0, v, 0x114, 0xf, 0xf, false); v += t;
  t = __builtin_amdgcn_update_dpp(0, v, 0x118, 0xf, 0xf, false); v += t;
  t = __builtin_amdgcn_update_dpp(0, v, 0x142, 0xf, 0xf, false); v += t;
  t = __builtin_amdgcn_update_dpp(0, v, 0x143, 0xf, 0xf, false); v += t;
  return __builtin_amdgcn_readlane(v, 63);
}
__device__ __forceinline__ void wave_red_top2(unsigned m1, unsigned m2,
                                              unsigned& r1, unsigned& r2) {
#define T2STEP(ctrl) { \
    unsigned o1 = (unsigned)__builtin_amdgcn_update_dpp(0, (int)m1, ctrl, 0xf, 0xf, false); \
    unsigned o2 = (unsigned)__builtin_amdgcn_update_dpp(0, (int)m2, ctrl, 0xf, 0xf, false); \
    unsigned tm = min(m1, o1); \
    m1 = max(m1, o1); \
    m2 = max(tm, max(m2, o2)); }
  T2STEP(0x111) T2STEP(0x112) T2STEP(0x114) T2STEP(0x118) T2STEP(0x142) T2STEP(0x143)
#undef T2STEP
  r1 = (unsigned)__builtin_amdgcn_readlane((int)m1, 63);
  r2 = (unsigned)__builtin_amdgcn_readlane((int)m2, 63);
}

// ---------------- K1: per-anchor max score -> w22 comparable keys ----------------
__global__ __launch_bounds__(256) void k_score(InPtrs P, unsigned* wkeys) {
  int gid = blockIdx.x * 256 + threadIdx.x;
  if (gid >= BATCH * (NA / 4)) return;
  int b = gid / (NA / 4);
  int q = gid - b * (NA / 4);
  int l = 0;
  while (q >= c_lvoff4[l + 1]) ++l;
  int hw = c_lh[l] * c_lw[l];
  int sp = (q - c_lvoff4[l]) * 4;
  const float4* cls = (const float4*)(P.cls[l] + (size_t)(b * NCLS) * hw + sp);
  int s4 = hw >> 2;
  float4 m = cls[0];
  for (int c = 1; c < NCLS; ++c) {
    float4 v = cls[(size_t)c * s4];
    m.x = fmaxf(m.x, v.x); m.y = fmaxf(m.y, v.y);
    m.z = fmaxf(m.z, v.z); m.w = fmaxf(m.w, v.w);
  }
  float4 lo = *(const float4*)(P.loc[l] + (size_t)b * hw + sp);
  float4 r;
  r.x = (sigf(lo.x) >= 0.01f) ? sigf(sigf(m.x)) : 0.0f;  // monotone: max commutes
  r.y = (sigf(lo.y) >= 0.01f) ? sigf(sigf(m.y)) : 0.0f;
  r.z = (sigf(lo.z) >= 0.01f) ? sigf(sigf(m.z)) : 0.0f;
  r.w = (sigf(lo.w) >= 0.01f) ? sigf(sigf(m.w)) : 0.0f;
  uint4 wq;
  wq.x = __float_as_uint(r.x) & 0x3FFFFFu;
  wq.y = __float_as_uint(r.y) & 0x3FFFFFu;
  wq.z = __float_as_uint(r.z) & 0x3FFFFFu;
  wq.w = __float_as_uint(r.w) & 0x3FFFFFu;
  ((uint4*)wkeys)[(size_t)b * (NA / 4) + q] = wq;
}

// ---------------- K2: exact top-1000 per batch, in top_k order ----------------
// V (exact 1000th key) via 22-round register binary search: countGE over
// register-held keys (no LDS scatter -> immune to the value clustering that
// serialized the histogram atomics; round-6 diagnostic). Per round: 20 reg
// compares + DPP wave sum + one parity-buffered slot write + ONE barrier +
// 16 broadcast reads. Then one-scan collect of >V, ==V ascending-index fill,
// hybrid register bitonic for final (score desc, idx asc) order.
__global__ __launch_bounds__(1024) void k_select(const unsigned* wkeys, int* sel) {
  int b = blockIdx.x;
  int tid = threadIdx.x;
  int wv = tid >> 6;
  int lane = tid & 63;
  __shared__ int s_cnt[2][16];        // parity-buffered per-wave counts
  __shared__ int s_wtot[16];
  __shared__ unsigned long long s_A[1024];
  __shared__ unsigned long long s_B[1024];
  const int NAq = NA / 4;

  // contiguous per-thread layout: thread t owns elements [20t, 20t+20)
  unsigned w[20];
  #pragma unroll
  for (int k = 0; k < 5; ++k) {
    int q = tid * 5 + k;
    uint4 u = (q < NAq) ? ((const uint4*)wkeys)[(size_t)b * NAq + q]
                        : make_uint4(0u, 0u, 0u, 0u);
    w[k * 4 + 0] = u.x; w[k * 4 + 1] = u.y; w[k * 4 + 2] = u.z; w[k * 4 + 3] = u.w;
  }
  int lim = NA - tid * 20;
  lim = (lim < 0) ? 0 : ((lim > 20) ? 20 : lim);

  int par = 0;
  auto countGE = [&](unsigned mid) -> int {   // mid >= 1: pads (w=0) never counted
    int c = 0;
    #pragma unroll
    for (int k = 0; k < 20; ++k) c += (w[k] >= mid) ? 1 : 0;
    c = wave_red_sum_i32(c);
    if (lane == 0) s_cnt[par][wv] = c;
    __syncthreads();
    int tot = 0;
    #pragma unroll
    for (int i = 0; i < 16; ++i) tot += s_cnt[par][i];
    par ^= 1;
    return tot;
  };

  unsigned V = 0u;                    // 0 => fewer than 1000 live keys
  if (countGE(WLIVE_LO) >= TOPK) {
    unsigned lo = WLIVE_LO, hi = WLIVE_HI;
    while (hi - lo > 1u) {
      unsigned mid = lo + (hi - lo) / 2u;
      if (countGE(mid) >= TOPK) lo = mid; else hi = mid;
    }
    V = lo;                           // countGE(V) >= 1000, countGE(V+1) < 1000
  }

  if (tid < 1024 - TOPK) s_A[TOPK + tid] = 0ull;  // pad slots (sink in desc sort)

  // ---- collect >V via ONE block prefix-scan (slot order arbitrary; bitonic sorts) ----
  int cgt = 0;
  #pragma unroll
  for (int k = 0; k < 20; ++k) cgt += (w[k] > V) ? 1 : 0;   // OOB w=0, never >V
  {
    int incl = cgt;
    #pragma unroll
    for (int o = 1; o < 64; o <<= 1) {
      int uu = __shfl_up(incl, o, 64);
      if (lane >= o) incl += uu;
    }
    if (lane == 63) s_wtot[wv] = incl;
    __syncthreads();
    int woff = 0, tot = 0;
    #pragma unroll
    for (int ww = 0; ww < 16; ++ww) { tot += s_wtot[ww]; woff += (ww < wv) ? s_wtot[ww] : 0; }
    int pos = woff + incl - cgt;
    #pragma unroll
    for (int k = 0; k < 20; ++k) {
      if (w[k] > V) {
        int i = tid * 20 + k;
        s_A[pos++] = ((unsigned long long)w[k] << 32) |
                     (unsigned long long)(0xFFFFFFFFu - (unsigned)i);
      }
    }
    int ngt = tot;
    int need = TOPK - ngt;            // >= 1; filled by ==V in ascending index order
    __syncthreads();                  // s_wtot reuse hazard fence

    // ---- ==V fill in ascending index order (from registers, contiguous layout) ----
    int ceq = 0;
    #pragma unroll
    for (int k = 0; k < 20; ++k) if (k < lim && w[k] == V) ++ceq;
    int incl2 = ceq;
    #pragma unroll
    for (int o = 1; o < 64; o <<= 1) {
      int uu = __shfl_up(incl2, o, 64);
      if (lane >= o) incl2 += uu;
    }
    if (lane == 63) s_wtot[wv] = incl2;
    __syncthreads();
    int woff2 = 0;
    #pragma unroll
    for (int ww = 0; ww < 16; ++ww) woff2 += (ww < wv) ? s_wtot[ww] : 0;
    int r = woff2 + incl2 - ceq;      // global exclusive prefix (index order)
    #pragma unroll
    for (int k = 0; k < 20; ++k) {
      if (k < lim && w[k] == V) {
        if (r < need) {
          int i = tid * 20 + k;
          s_A[ngt + r] = ((unsigned long long)V << 32) |
                         (unsigned long long)(0xFFFFFFFFu - (unsigned)i);
        }
        ++r;
      }
    }
  }
  __syncthreads();

  // hybrid bitonic sort, descending, one key/thread in registers.
  unsigned long long key = s_A[tid];
  int tog = 0;
  for (unsigned k = 2; k <= 1024; k <<= 1) {
    for (unsigned j = k >> 1; j > 0; j >>= 1) {
      unsigned long long other;
      if (j >= 64) {
        unsigned long long* cur = tog ? s_A : s_B;
        cur[tid] = key;
        __syncthreads();
        other = cur[tid ^ (int)j];
        tog ^= 1;
      } else {
        other = __shfl_xor(key, (int)j, 64);
      }
      bool takeMax = (((tid & (int)k) == 0) == ((tid & (int)j) == 0));
      unsigned long long mx = (key > other) ? key : other;
      unsigned long long mn = (key > other) ? other : key;
      key = takeMax ? mx : mn;
    }
  }
  if (tid < TOPK) {
    sel[b * TOPK + tid] = (int)(0xFFFFFFFFu - (unsigned)(key & 0xFFFFFFFFull));
  }
}

// ---------------- K3: decode boxes + 80 class scores, one WAVE per row ----------
__global__ __launch_bounds__(256) void k_gather(InPtrs P, const int* sel, float* boxes, float* sv) {
  int wvi = threadIdx.x >> 6;
  int lane = threadIdx.x & 63;
  int wid = blockIdx.x * 4 + wvi;
  int b = wid / TOPK;
  int r = wid - b * TOPK;
  __shared__ float s_sc[4][NCLS];

  int a = sel[b * TOPK + r];
  int l = 0;
  while (a >= c_lvoff[l + 1]) ++l;
  int within = a - c_lvoff[l];
  int W = c_lw[l], H = c_lh[l];
  int y = within / W, x = within - y * W;
  int hw = H * W;
  int sp = within;
  float stride = c_ls[l];
  float px = (float)x * stride;
  float py = (float)y * stride;
  float pw = 4.0f * stride;

  const float* shp = P.shp[l];
  float dws = shp[(b * 2 + 0) * hw + sp];
  float dhs = shp[(b * 2 + 1) * hw + sp];
  dws = fminf(fmaxf(dws, -MAX_RATIO_ANCHOR), MAX_RATIO_ANCHOR);
  dhs = fminf(fmaxf(dhs, -MAX_RATIO_ANCHOR), MAX_RATIO_ANCHOR);
  float gw = pw * expf(dws);
  float gh = pw * expf(dhs);
  float ax1 = px - 0.5f * gw, ax2 = px + 0.5f * gw;
  float ay1 = py - 0.5f * gh, ay2 = py + 0.5f * gh;

  const float* bb = P.bbox[l];
  float dx = bb[(b * 4 + 0) * hw + sp];
  float dy = bb[(b * 4 + 1) * hw + sp];
  float dw = bb[(b * 4 + 2) * hw + sp];
  float dh = bb[(b * 4 + 3) * hw + sp];
  dw = fminf(fmaxf(dw, -MAX_RATIO_BBOX), MAX_RATIO_BBOX);
  dh = fminf(fmaxf(dh, -MAX_RATIO_BBOX), MAX_RATIO_BBOX);
  float px2 = (ax1 + ax2) * 0.5f, py2 = (ay1 + ay2) * 0.5f;
  float pw2 = ax2 - ax1, ph2 = ay2 - ay1;
  float gx = px2 + pw2 * dx, gy = py2 + ph2 * dy;
  float gw2 = pw2 * expf(dw), gh2 = ph2 * expf(dh);
  float x1 = fminf(fmaxf(gx - 0.5f * gw2, 0.0f), IMG_WF);
  float x2 = fminf(fmaxf(gx + 0.5f * gw2, 0.0f), IMG_WF);
  float y1 = fminf(fmaxf(gy - 0.5f * gh2, 0.0f), IMG_HF);
  float y2 = fminf(fmaxf(gy + 0.5f * gh2, 0.0f), IMG_HF);
  if (lane == 0) {
    float4 st; st.x = x1; st.y = y1; st.z = x2; st.w = y2;
    ((float4*)boxes)[b * TOPK + r] = st;
  }

  const float* cls = P.cls[l];
  float sl = sigf(P.loc[l][b * hw + sp]);
  bool mask = (sl >= 0.01f);
  int base = (b * NCLS) * hw + sp;
  for (int c = lane; c < NCLS; c += 64) {
    float vv = 0.0f;
    if (mask) {
      float s2 = sigf(sigf(cls[base + c * hw]));
      vv = (s2 > 0.05f) ? s2 : 0.0f;   // SCORE_THR (strict >)
    }
    s_sc[wvi][c] = vv;
  }
  __syncthreads();
  int t = threadIdx.x;
  if (t < NCLS) {
    int r0 = blockIdx.x * 4 - b * TOPK;
    float4 o; o.x = s_sc[0][t]; o.y = s_sc[1][t]; o.z = s_sc[2][t]; o.w = s_sc[3][t];
    *(float4*)(sv + ((size_t)(b * NCLS + t) * TOPK + r0)) = o;
  }
}

// ---------------- K4: per-(batch,class) greedy NMS, FOUR waves, TWO picks/round --
__global__ __launch_bounds__(256) void k_nms(const float* boxes, const float* sv,
                                             float* keptScore, int* keptRow, int* kc,
                                             const int* flags, const int* gbits, int cap) {
  int bc = blockIdx.x;
  if (flags && flags[bc] == 0) return;   // uniform early-exit (fixup pass)
  int b = bc / NCLS;
  int c = bc - b * NCLS;
  int tid = threadIdx.x;
  int wv = tid >> 6, lane = tid & 63;

  unsigned Glow = 0u;
  if (gbits) Glow = ((unsigned)gbits[b]) & 0x3FFFFFu;

  __shared__ float4 s_box[TOPK];
  __shared__ float  s_ard[TOPK];
  __shared__ unsigned long long s_p2[2][4];

  float x1[4], y1[4], x2[4], y2[4], ar[4];
  unsigned key[4];
  float off = (float)c * CLS_OFF;
  const float* svc = sv + (size_t)(b * NCLS + c) * TOPK;
  #pragma unroll
  for (int j = 0; j < 4; ++j) {
    int row = j * 256 + tid;
    if (row < TOPK) {
      float4 bo = ((const float4*)boxes)[b * TOPK + row];
      float a = bo.x + off, d = bo.y + off, e = bo.z + off, f = bo.w + off;
      x1[j] = a; y1[j] = d; x2[j] = e; y2[j] = f;
      ar[j] = (e - a) * (f - d);
      unsigned bits = __float_as_uint(svc[row]);
      key[j] = ((bits & 0x3FFFFFu) << 10) | (1023u - (unsigned)row);
      float sden = ar[j] + 1e-6f;
      bool deg = !((double)ar[j] > (double)sden * K2_HALF_UP);
      float4 sb; sb.x = a; sb.y = d; sb.z = e; sb.w = f;
      s_box[row] = sb;
      s_ard[row] = __uint_as_float(__float_as_uint(ar[j]) | (deg ? 0x80000000u : 0u));
    } else {
      x1[j] = y1[j] = x2[j] = y2[j] = ar[j] = 0.0f;
      key[j] = 0u;
    }
  }
  __syncthreads();

  int kept = 0;
  bool sticky = false;
  float* ks = keptScore + (size_t)(b * NCLS + c) * MAXPER;
  int*   kr = keptRow   + (size_t)(b * NCLS + c) * MAXPER;

  for (int round = 0; round < cap; ++round) {
    int par = round & 1;
    unsigned hi1 = max(key[0], key[1]), lo1 = min(key[0], key[1]);
    unsigned hi2 = max(key[2], key[3]), lo2 = min(key[2], key[3]);
    unsigned m1 = max(hi1, hi2);
    unsigned m2 = max(min(hi1, hi2), max(lo1, lo2));
    unsigned w1, w2;
    wave_red_top2(m1, m2, w1, w2);
    if (lane == 0) s_p2[par][wv] = ((unsigned long long)w1 << 32) | w2;
    __syncthreads();
    unsigned k0 = 0u, k1 = 0u;
    #pragma unroll
    for (int w = 0; w < 4; ++w) {
      unsigned long long pp = s_p2[par][w];
      unsigned p1 = (unsigned)(pp >> 32), p2 = (unsigned)pp;
      unsigned tm = min(k0, p1);
      k0 = max(k0, p1);
      k1 = max(tm, max(k1, p2));
    }
    if (k0 < 1024u) break;
    if ((k0 >> 10) < Glow) break;
    int brow1 = 1023 - (int)(k0 & 1023u);
    float bs1 = __uint_as_float(0x3F000000u | (k0 >> 10));
    float4 bb1 = s_box[brow1];
    unsigned au1 = __float_as_uint(s_ard[brow1]);
    bool deg1 = (au1 >> 31) != 0u;
    float ba1 = __uint_as_float(au1 & 0x7FFFFFFFu);
    if (tid == 0) { ks[kept] = bs1; kr[kept] = brow1; }
    kept++;
    if (deg1) { sticky = true; break; }
    if (kept >= cap) break;
    bool live2 = (k1 >= 1024u) && ((k1 >> 10) >= Glow);
    if (!live2) break;
    bool do2 = false, deg2 = false;
    float4 bb2; float ba2 = 0.0f;
    {
      int brow2 = 1023 - (int)(k1 & 1023u);
      float bs2 = __uint_as_float(0x3F000000u | (k1 >> 10));
      bb2 = s_box[brow2];
      unsigned au2 = __float_as_uint(s_ard[brow2]);
      deg2 = (au2 >> 31) != 0u;
      ba2 = __uint_as_float(au2 & 0x7FFFFFFFu);
      float ltx = fmaxf(bb1.x, bb2.x), rbx = fminf(bb1.z, bb2.z);
      float lty = fmaxf(bb1.y, bb2.y), rby = fminf(bb1.w, bb2.w);
      float w_ = fmaxf(rbx - ltx, 0.0f), h_ = fmaxf(rby - lty, 0.0f);
      float inter = w_ * h_;
      float denom = ((ba1 + ba2) - inter) + 1e-6f;
      if (!((double)inter > (double)denom * K2_HALF_UP)) {
        do2 = true;
        if (tid == 0) { ks[kept] = bs2; kr[kept] = brow2; }
        kept++;
      }
    }
    if (do2 && deg2) { sticky = true; break; }
    #pragma unroll
    for (int j = 0; j < 4; ++j) {
      {
        float ltx = fmaxf(bb1.x, x1[j]), rbx = fminf(bb1.z, x2[j]);
        float lty = fmaxf(bb1.y, y1[j]), rby = fminf(bb1.w, y2[j]);
        float w_ = fmaxf(rbx - ltx, 0.0f), h_ = fmaxf(rby - lty, 0.0f);
        float inter = w_ * h_;
        float denom = ((ba1 + ar[j]) - inter) + 1e-6f;
        if ((double)inter > (double)denom * K2_HALF_UP) key[j] = 0u;
      }
      if (do2) {
        float ltx = fmaxf(bb2.x, x1[j]), rbx = fminf(bb2.z, x2[j]);
        float lty = fmaxf(bb2.y, y1[j]), rby = fminf(bb2.w, y2[j]);
        float w_ = fmaxf(rbx - ltx, 0.0f), h_ = fmaxf(rby - lty, 0.0f);
        float inter = w_ * h_;
        float denom = ((ba2 + ar[j]) - inter) + 1e-6f;
        if ((double)inter > (double)denom * K2_HALF_UP) key[j] = 0u;
      }
    }
    if (kept >= cap) break;
  }
  if (tid == 0) kc[b * NCLS + c] = sticky ? -kept : kept;
}

// ---------------- K4b: fixup decision + per-batch G (histogram kept: T<=640) ----
__global__ __launch_bounds__(256) void k_cut(const float* keptScore, const int* kc,
                                             int* flags, int* gbits) {
  int b = blockIdx.x;
  int tid = threadIdx.x;
  int wv = tid >> 6, lane = tid & 63;
  __shared__ int s_abs[NCLS];
  __shared__ int s_neg[NCLS];
  __shared__ unsigned s_h[2048];
  __shared__ int s_wtot[4];
  __shared__ int s_res[2];
  __shared__ int s_tot[4];

  if (tid < NCLS) {
    int v = kc[b * NCLS + tid];
    s_abs[tid] = (v < 0) ? -v : v;
    s_neg[tid] = (v < 0) ? 1 : 0;
  }
  #pragma unroll
  for (int j = 0; j < 8; ++j) s_h[tid * 8 + j] = 0u;
  __syncthreads();

  unsigned vv[3] = {0u, 0u, 0u};
  #pragma unroll
  for (int t = 0; t < 3; ++t) {
    int e = tid + t * 256;
    if (e < NCLS * CAP) {
      int c = e / CAP, k = e - c * CAP;
      if (k < s_abs[c])
        vv[t] = __float_as_uint(keptScore[(size_t)b * NCLS * MAXPER + c * MAXPER + k])
                & 0x3FFFFFu;
    }
  }
  int live = ((vv[0] != 0u) ? 1 : 0) + ((vv[1] != 0u) ? 1 : 0) + ((vv[2] != 0u) ? 1 : 0);
  live = wave_red_sum_i32(live);
  if (lane == 0) s_tot[wv] = live;
  #pragma unroll
  for (int t = 0; t < 3; ++t) if (vv[t]) atomicAdd(&s_h[vv[t] >> 11], 1u);
  __syncthreads();
  int T = s_tot[0] + s_tot[1] + s_tot[2] + s_tot[3];

  auto scanFind = [&](int target) {
    int base = 2047 - 8 * tid;
    int h[8]; int loc = 0;
    #pragma unroll
    for (int j = 0; j < 8; ++j) { h[j] = (int)s_h[base - j]; loc += h[j]; }
    int incl = loc;
    #pragma unroll
    for (int o = 1; o < 64; o <<= 1) {
      int uu = __shfl_up(incl, o, 64);
      if (lane >= o) incl += uu;
    }
    if (lane == 63) s_wtot[wv] = incl;
    __syncthreads();
    int woff = 0;
    #pragma unroll
    for (int ww = 0; ww < 4; ++ww) woff += (ww < wv) ? s_wtot[ww] : 0;
    int e = woff + incl - loc;
    #pragma unroll
    for (int j = 0; j < 8; ++j) {
      if (e < target && e + h[j] >= target) { s_res[0] = base - j; s_res[1] = e; }
      e += h[j];
    }
    __syncthreads();
  };

  unsigned G = 0u;
  if (T >= MAXPER) {
    scanFind(MAXPER);
    int B1 = s_res[0], NGT1 = s_res[1];
    #pragma unroll
    for (int j = 0; j < 8; ++j) s_h[tid * 8 + j] = 0u;
    __syncthreads();
    #pragma unroll
    for (int t = 0; t < 3; ++t)
      if (vv[t] && (int)(vv[t] >> 11) == B1) atomicAdd(&s_h[vv[t] & 0x7FFu], 1u);
    __syncthreads();
    scanFind(MAXPER - NGT1);
    G = 0x3F000000u | ((unsigned)B1 << 11) | (unsigned)s_res[0];
  }
  if (tid == 0) gbits[b] = (int)G;
  if (tid < NCLS) {
    int f = 0;
    if (s_abs[tid] == CAP && !s_neg[tid]) {
      unsigned slast = __float_as_uint(
          keptScore[(size_t)b * NCLS * MAXPER + tid * MAXPER + (CAP - 1)]);
      if (slast >= G) f = 1;
    }
    flags[b * NCLS + tid] = f;
  }
}

// ---------------- K5: sort-based merge -> top-100 (rank-by-count) ----------------
// Pool threshold V (exact 100th stream score) via 22-round register binary
// search (round-6 diagnostic: the clustered-value LDS histogram atomics were
// ~13 us of this kernel's 15.7 us). countGE is distribution-insensitive.
__global__ __launch_bounds__(256) void k_merge(const float* boxes, const float* keptScore,
                                               const int* keptRow, const int* kc, float* out) {
  int b = blockIdx.x;
  int tid = threadIdx.x;
  int wv = tid >> 6, lane = tid & 63;
  __shared__ int s_kc[NCLS];
  __shared__ int s_cnt[2][4];          // parity-buffered per-wave counts
  __shared__ int s_pos;
  __shared__ int s_sticky;
  __shared__ int s_navail;
  __shared__ unsigned long long s_pool[POOL];     // 2 KB
  __shared__ unsigned long long s_sorted[POOL];   // 2 KB

  for (int c = tid; c < NCLS; c += 256) s_kc[c] = kc[b * NCLS + c];
  if (tid == 0) { s_pos = 0; s_sticky = 0x7FFFFFFF; s_navail = 0; }
  for (int i = tid; i < POOL; i += 256) { s_pool[i] = 0ull; s_sorted[i] = 0ull; }
  __syncthreads();

  // load all stream scores as w22 into registers (coalesced; invalid -> 0)
  unsigned sc[32];
  #pragma unroll
  for (int s = 0; s < 32; ++s) {
    int i = tid + s * 256;
    unsigned vvv = 0u;
    if (i < NCLS * MAXPER) {
      int c = i / MAXPER, k = i - c * MAXPER;
      int kcv = s_kc[c];
      int ka = (kcv < 0) ? -kcv : kcv;
      if (k < ka)
        vvv = __float_as_uint(keptScore[(size_t)b * NCLS * MAXPER + i]) & 0x3FFFFFu;
    }
    sc[s] = vvv;
  }

  int par = 0;
  auto countGE = [&](unsigned mid) -> int {   // mid >= 1: dead (0) never counted
    int c = 0;
    #pragma unroll
    for (int s = 0; s < 32; ++s) c += (sc[s] >= mid) ? 1 : 0;
    c = wave_red_sum_i32(c);
    if (lane == 0) s_cnt[par][wv] = c;
    __syncthreads();
    int tot = s_cnt[par][0] + s_cnt[par][1] + s_cnt[par][2] + s_cnt[par][3];
    par ^= 1;
    return tot;
  };

  int T = countGE(WLIVE_LO);           // total stream entries
  unsigned V = WLIVE_LO;               // all live pass if T <= 100
  if (T > MAXPER) {
    unsigned lo = WLIVE_LO, hi = WLIVE_HI;
    while (hi - lo > 1u) {
      unsigned mid = lo + (hi - lo) / 2u;
      if (countGE(mid) >= MAXPER) lo = mid; else hi = mid;
    }
    V = lo;   // count(>=V) >= 100, count(>V) < 100
  }

  // gather candidate pool (>= V)
  #pragma unroll
  for (int s = 0; s < 32; ++s) {
    if (sc[s] >= V && sc[s] != 0u) {
      int i = tid + s * 256;
      int c = i / MAXPER, k = i - c * MAXPER;
      int kcv = s_kc[c];
      int ka = (kcv < 0) ? -kcv : kcv;
      unsigned st = (kcv < 0 && k == ka - 1) ? 1u : 0u;
      unsigned row = (unsigned)keptRow[(size_t)b * NCLS * MAXPER + i];
      unsigned flat = row * 80u + (unsigned)c;
      int p = atomicAdd(&s_pos, 1);
      if (p < POOL)
        s_pool[p] = ((unsigned long long)(0x3F000000u | sc[s]) << 32) |
                    (unsigned long long)(0x7FFFFFFFu - ((flat << 1) | st));
    }
  }
  __syncthreads();

  // rank-by-count (keys unique via flat index; zeros excluded -> ranks contiguous)
  if (tid < POOL) {
    unsigned long long mykey = s_pool[tid];
    if (mykey != 0ull) {
      int rank = 0;
      #pragma unroll 8
      for (int s = 0; s < POOL; ++s) rank += (s_pool[s] > mykey) ? 1 : 0;
      s_sorted[rank] = mykey;
    }
  }
  __syncthreads();

  if (tid < MAXPER) {
    unsigned long long key = s_sorted[tid];
    if (key != 0ull) {
      atomicAdd(&s_navail, 1);
      if ((((unsigned)key) & 1u) == 0u) atomicMin(&s_sticky, tid);
    }
  }
  __syncthreads();
  int navail = s_navail;
  int p = s_sticky;
  int n = (p < navail) ? MAXPER : navail;

  if (tid == 0) out[b] = (float)n;
  const int OB = BATCH;
  const int OP = OB + BATCH * MAXPER * 4;
  const int OS = OP + BATCH * MAXPER;
  if (tid < MAXPER) {
    int k = tid;
    float bx0 = 0.f, bx1 = 0.f, bx2 = 0.f, bx3 = 0.f, scf = 0.f, cf = -1.0f;
    if (k < n) {
      int idx = (k > p) ? p : k;
      unsigned long long key = s_sorted[idx];
      unsigned flat = (0x7FFFFFFFu - (unsigned)key) >> 1;
      unsigned cls = flat % 80u;
      unsigned row = flat / 80u;
      float4 bo = ((const float4*)boxes)[b * TOPK + row];
      bx0 = bo.x; bx1 = bo.y; bx2 = bo.z; bx3 = bo.w;
      scf = __uint_as_float((unsigned)(key >> 32));
      cf = (float)cls;
    }
    float* po = out + OB + (size_t)(b * MAXPER + k) * 4;
    po[0] = bx0; po[1] = bx1; po[2] = bx2; po[3] = bx3;
    out[OP + b * MAXPER + k] = scf;
    out[OS + b * MAXPER + k] = cf;
  }
}

extern "C" void kernel_launch(void* const* d_in, const int* in_sizes, int n_in,
                              void* d_out, int out_size, void* d_ws, size_t ws_size,
                              hipStream_t stream) {
  InPtrs P;
  for (int l = 0; l < 5; ++l) {
    P.cls[l]  = (const float*)d_in[4 * l + 0];
    P.bbox[l] = (const float*)d_in[4 * l + 1];
    P.shp[l]  = (const float*)d_in[4 * l + 2];
    P.loc[l]  = (const float*)d_in[4 * l + 3];
  }
  unsigned* wkeys  = (unsigned*)d_ws;                       // B*NA
  int*   sel       = (int*)(wkeys + BATCH * NA);            // B*TOPK
  float* boxes     = (float*)(sel + BATCH * TOPK);          // B*TOPK*4 (16B aligned)
  float* sv        = boxes + BATCH * TOPK * 4;              // B*80*TOPK (class-major)
  float* keptScore = sv + BATCH * NCLS * TOPK;              // B*80*100
  int*   keptRow   = (int*)(keptScore + BATCH * NCLS * MAXPER);
  int*   kc        = keptRow + BATCH * NCLS * MAXPER;
  int*   flags     = kc + BATCH * NCLS;
  int*   gbits     = flags + BATCH * NCLS;
  float* out = (float*)d_out;

  k_score<<<(BATCH * (NA / 4) + 255) / 256, 256, 0, stream>>>(P, wkeys);
  k_select<<<BATCH, 1024, 0, stream>>>(wkeys, sel);
  k_gather<<<BATCH * TOPK / 4, 256, 0, stream>>>(P, sel, boxes, sv);
  k_nms<<<BATCH * NCLS, 256, 0, stream>>>(boxes, sv, keptScore, keptRow, kc,
                                          (const int*)nullptr, (const int*)nullptr, CAP);
  k_cut<<<BATCH, 256, 0, stream>>>(keptScore, kc, flags, gbits);
  k_nms<<<BATCH * NCLS, 256, 0, stream>>>(boxes, sv, keptScore, keptRow, kc,
                                          flags, gbits, MAXPER);
  k_merge<<<BATCH, 256, 0, stream>>>(boxes, keptScore, keptRow, kc, out);
}

// Round 8
// 194.712 us; speedup vs baseline: 2.9902x; 1.0993x over previous
//
#include <hip/hip_runtime.h>
#include <stdint.h>

#define NCLS 80
#define BATCH 8
#define NA 20460          // total anchors per image across 5 levels
#define TOPK 1000
#define MAXPER 100
#define CAP 8             // capped per-class NMS depth (exact fixup via flags)
#define POOL 256          // merge candidate pool (top-100 + tie slack)
#define IMG_WF 1280.0f
#define IMG_HF 768.0f
#define CLS_OFF 4096.0f
#define MAX_RATIO_ANCHOR 13.815510557964274f  // |log(1e-6)|
#define MAX_RATIO_BBOX   4.1351665567423557f  // |log(16/1000)|

// RN(a/b) > 0.5  <=>  a > b*(0.5 + 2^-25) as reals (0.5 mantissa even, tie->down).
// b has 24-bit mantissa, K2 has 25 -> product exact in f64; comparison exact.
#define K2_HALF_UP (0.5 + 0x1p-25)

__constant__ int   c_lvoff[6]  = {0, 15360, 19200, 20160, 20400, 20460};
__constant__ int   c_lvoff4[6] = {0, 3840, 4800, 5040, 5100, 5115};   // /4
__constant__ int   c_lw[5]    = {160, 80, 40, 20, 10};
__constant__ int   c_lh[5]    = {96, 48, 24, 12, 6};
__constant__ float c_ls[5]    = {8.f, 16.f, 32.f, 64.f, 128.f};

struct InPtrs {
  const float* cls[5];
  const float* bbox[5];
  const float* shp[5];
  const float* loc[5];
};

__device__ __forceinline__ float sigf(float x) { return 1.0f / (1.0f + expf(-x)); }

// ---- DPP wave64 reductions (VALU-only) ----
__device__ __forceinline__ int wave_red_sum_i32(int v) {
  int t;
  t = __builtin_amdgcn_update_dpp(0, v, 0x111, 0xf, 0xf, false); v += t;
  t = __builtin_amdgcn_update_dpp(0, v, 0x112, 0xf, 0xf, false); v += t;
  t = __builtin_amdgcn_update_dpp(0, v, 0x114, 0xf, 0xf, false); v += t;
  t = __builtin_amdgcn_update_dpp(0, v, 0x118, 0xf, 0xf, false); v += t;
  t = __builtin_amdgcn_update_dpp(0, v, 0x142, 0xf, 0xf, false); v += t;
  t = __builtin_amdgcn_update_dpp(0, v, 0x143, 0xf, 0xf, false); v += t;
  return __builtin_amdgcn_readlane(v, 63);
}
// top-2 of the wave's values: merge over disjoint sets; exact.
__device__ __forceinline__ void wave_red_top2(unsigned m1, unsigned m2,
                                              unsigned& r1, unsigned& r2) {
#define T2STEP(ctrl) { \
    unsigned o1 = (unsigned)__builtin_amdgcn_update_dpp(0, (int)m1, ctrl, 0xf, 0xf, false); \
    unsigned o2 = (unsigned)__builtin_amdgcn_update_dpp(0, (int)m2, ctrl, 0xf, 0xf, false); \
    unsigned tm = min(m1, o1); \
    m1 = max(m1, o1); \
    m2 = max(tm, max(m2, o2)); }
  T2STEP(0x111) T2STEP(0x112) T2STEP(0x114) T2STEP(0x118) T2STEP(0x142) T2STEP(0x143)
#undef T2STEP
  r1 = (unsigned)__builtin_amdgcn_readlane((int)m1, 63);
  r2 = (unsigned)__builtin_amdgcn_readlane((int)m2, 63);
}

// ---------------- K1: per-anchor max score, 4-way class split + shfl combine ----
// 640 blocks (vs 160): lanes 4p..4p+3 each reduce 20 classes of anchor-quad p,
// combine via two xor-max steps (max is grouping-exact; this 4-way grouping was
// verified bit-exact in an earlier round), lane h=0 applies loc mask + double
// sigmoid and writes. Same 52.7 MB read at 4x the wave-level concurrency, no
// global partial round-trip (the failure mode of the earlier split attempt).
__global__ __launch_bounds__(256) void k_maxscore(InPtrs P, float* maxscore) {
  int gid = blockIdx.x * 256 + threadIdx.x;
  int p = gid >> 2;                    // anchor-quad id
  int h = gid & 3;                     // class chunk: [20h, 20h+20)
  if (p >= BATCH * (NA / 4)) return;   // tail groups of 4 are wholly inactive
  int b = p / (NA / 4);
  int q = p - b * (NA / 4);            // float4 index within batch (level-merged)
  int l = 0;
  while (q >= c_lvoff4[l + 1]) ++l;
  int hw = c_lh[l] * c_lw[l];
  int sp = (q - c_lvoff4[l]) * 4;
  const float4* cls = (const float4*)(P.cls[l] + (size_t)(b * NCLS + h * 20) * hw + sp);
  int s4 = hw >> 2;                    // class stride in float4 units
  float4 m = cls[0];
  for (int c = 1; c < NCLS / 4; ++c) {
    float4 v = cls[(size_t)c * s4];
    m.x = fmaxf(m.x, v.x); m.y = fmaxf(m.y, v.y);
    m.z = fmaxf(m.z, v.z); m.w = fmaxf(m.w, v.w);
  }
  #pragma unroll
  for (int o = 1; o < 4; o <<= 1) {    // combine 4 chunks within the lane quad
    m.x = fmaxf(m.x, __shfl_xor(m.x, o, 64));
    m.y = fmaxf(m.y, __shfl_xor(m.y, o, 64));
    m.z = fmaxf(m.z, __shfl_xor(m.z, o, 64));
    m.w = fmaxf(m.w, __shfl_xor(m.w, o, 64));
  }
  if (h == 0) {
    float4 lo = *(const float4*)(P.loc[l] + (size_t)b * hw + sp);
    float4 r;
    r.x = (sigf(lo.x) >= 0.01f) ? sigf(sigf(m.x)) : 0.0f;  // monotone: max commutes
    r.y = (sigf(lo.y) >= 0.01f) ? sigf(sigf(m.y)) : 0.0f;
    r.z = (sigf(lo.z) >= 0.01f) ? sigf(sigf(m.z)) : 0.0f;
    r.w = (sigf(lo.w) >= 0.01f) ? sigf(sigf(m.w)) : 0.0f;
    ((float4*)maxscore)[(size_t)b * (NA / 4) + q] = r;
  }
}

// ---------------- K2: exact top-1000 per batch, in top_k order ----------------
// Live scores sig(sig(x)) lie in (0.5, 0.734375): float bits [0x3F000001,
// 0x3F3C0000) -> bits[31:22] fixed. Comparable key w = bits & 0x3FFFFF (0 for
// dead), strictly monotone with float order. Two-level 2048-bucket LDS radix
// histogram + shfl suffix-scan finds the exact 1000th key V (empirically the
// fastest variant: beats the 22-round barrier binary search by ~10 us). OOB
// pads land in bucket (0,0) = bottom of the descending order. One-scan collect
// of >V, ==V fill in ascending index order, hybrid register bitonic for the
// final (score desc, idx asc) top_k order.
__global__ __launch_bounds__(1024) void k_select(const float* maxscore, int* sel) {
  int b = blockIdx.x;
  const unsigned int* ms = (const unsigned int*)(maxscore + (size_t)b * NA);
  int tid = threadIdx.x;
  int wv = tid >> 6;
  int lane = tid & 63;
  __shared__ unsigned s_h[2048];      // level-1 then level-2 histogram (8 KB)
  __shared__ int s_wtot[16];
  __shared__ int s_res[2];            // {bucket, count-above} from scanFind
  __shared__ unsigned long long s_A[1024];
  __shared__ unsigned long long s_B[1024];

  // contiguous per-thread layout: thread t owns elements [20t, 20t+20)
  unsigned w[20];
  #pragma unroll
  for (int k = 0; k < 5; ++k) {
    int q = tid * 5 + k;
    uint4 u = (q < NA / 4) ? ((const uint4*)ms)[q] : make_uint4(0u, 0u, 0u, 0u);
    w[k * 4 + 0] = u.x & 0x3FFFFFu;
    w[k * 4 + 1] = u.y & 0x3FFFFFu;
    w[k * 4 + 2] = u.z & 0x3FFFFFu;
    w[k * 4 + 3] = u.w & 0x3FFFFFu;
  }
  int lim = NA - tid * 20;            // valid element count for this thread
  lim = (lim < 0) ? 0 : ((lim > 20) ? 20 : lim);

  s_h[tid] = 0u; s_h[tid + 1024] = 0u;
  __syncthreads();

  // descending-order crossing: unique bucket B with cntAbove(B) < target <= cntAbove(B)+h[B]
  auto scanFind = [&](int target) {
    int b0 = 2047 - 2 * tid;          // thread t owns descending positions 2t, 2t+1
    int h0 = (int)s_h[b0];
    int h1 = (int)s_h[b0 - 1];
    int pair = h0 + h1;
    int incl = pair;
    #pragma unroll
    for (int o = 1; o < 64; o <<= 1) {
      int uu = __shfl_up(incl, o, 64);
      if (lane >= o) incl += uu;
    }
    if (lane == 63) s_wtot[wv] = incl;
    __syncthreads();
    int woff = 0;
    #pragma unroll
    for (int ww = 0; ww < 16; ++ww) woff += (ww < wv) ? s_wtot[ww] : 0;
    int excl = woff + incl - pair;    // count in buckets strictly above b0
    if (excl < target && excl + h0 >= target) { s_res[0] = b0; s_res[1] = excl; }
    int e1 = excl + h0;
    if (e1 < target && e1 + h1 >= target) { s_res[0] = b0 - 1; s_res[1] = e1; }
    __syncthreads();
  };

  // ---- level 1: bucket = w >> 11 ----
  #pragma unroll
  for (int k = 0; k < 20; ++k) atomicAdd(&s_h[w[k] >> 11], 1u);
  __syncthreads();
  scanFind(TOPK);
  int B1 = s_res[0];
  int NGT1 = s_res[1];                // count of keys in buckets > B1 (< 1000)

  // ---- level 2: low 11 bits within bucket B1 ----
  s_h[tid] = 0u; s_h[tid + 1024] = 0u;
  __syncthreads();
  #pragma unroll
  for (int k = 0; k < 20; ++k)
    if ((int)(w[k] >> 11) == B1) atomicAdd(&s_h[w[k] & 0x7FFu], 1u);
  __syncthreads();
  scanFind(TOPK - NGT1);
  unsigned V = ((unsigned)B1 << 11) | (unsigned)s_res[0];  // exact 1000th key

  if (tid < 1024 - TOPK) s_A[TOPK + tid] = 0ull;  // pad slots (sink in desc sort)

  // ---- collect >V via ONE block prefix-scan (slot order arbitrary; bitonic sorts) ----
  int cgt = 0;
  #pragma unroll
  for (int k = 0; k < 20; ++k) cgt += (w[k] > V) ? 1 : 0;   // OOB w=0, never >V
  {
    int incl = cgt;
    #pragma unroll
    for (int o = 1; o < 64; o <<= 1) {
      int uu = __shfl_up(incl, o, 64);
      if (lane >= o) incl += uu;
    }
    if (lane == 63) s_wtot[wv] = incl;
    __syncthreads();
    int woff = 0, tot = 0;
    #pragma unroll
    for (int ww = 0; ww < 16; ++ww) { tot += s_wtot[ww]; woff += (ww < wv) ? s_wtot[ww] : 0; }
    int pos = woff + incl - cgt;
    #pragma unroll
    for (int k = 0; k < 20; ++k) {
      if (w[k] > V) {
        int i = tid * 20 + k;
        s_A[pos++] = ((unsigned long long)w[k] << 32) |
                     (unsigned long long)(0xFFFFFFFFu - (unsigned)i);
      }
    }
    int ngt = tot;
    int need = TOPK - ngt;            // >= 1; filled by ==V in ascending index order
    __syncthreads();                  // s_wtot reuse hazard fence

    // ---- ==V fill in ascending index order (from registers, contiguous layout) ----
    int ceq = 0;
    #pragma unroll
    for (int k = 0; k < 20; ++k) if (k < lim && w[k] == V) ++ceq;
    int incl2 = ceq;
    #pragma unroll
    for (int o = 1; o < 64; o <<= 1) {
      int uu = __shfl_up(incl2, o, 64);
      if (lane >= o) incl2 += uu;
    }
    if (lane == 63) s_wtot[wv] = incl2;
    __syncthreads();
    int woff2 = 0;
    #pragma unroll
    for (int ww = 0; ww < 16; ++ww) woff2 += (ww < wv) ? s_wtot[ww] : 0;
    int r = woff2 + incl2 - ceq;      // global exclusive prefix (index order)
    #pragma unroll
    for (int k = 0; k < 20; ++k) {
      if (k < lim && w[k] == V) {
        if (r < need) {
          int i = tid * 20 + k;
          s_A[ngt + r] = ((unsigned long long)V << 32) |
                         (unsigned long long)(0xFFFFFFFFu - (unsigned)i);
        }
        ++r;
      }
    }
  }
  __syncthreads();

  // hybrid bitonic sort, descending, one key/thread in registers.
  unsigned long long key = s_A[tid];
  int tog = 0;   // 0 -> s_B first (s_A holds live data at entry)
  for (unsigned k = 2; k <= 1024; k <<= 1) {
    for (unsigned j = k >> 1; j > 0; j >>= 1) {
      unsigned long long other;
      if (j >= 64) {
        unsigned long long* cur = tog ? s_A : s_B;
        cur[tid] = key;
        __syncthreads();
        other = cur[tid ^ (int)j];
        tog ^= 1;
      } else {
        other = __shfl_xor(key, (int)j, 64);
      }
      bool takeMax = (((tid & (int)k) == 0) == ((tid & (int)j) == 0));
      unsigned long long mx = (key > other) ? key : other;
      unsigned long long mn = (key > other) ? other : key;
      key = takeMax ? mx : mn;
    }
  }
  if (tid < TOPK) {
    sel[b * TOPK + tid] = (int)(0xFFFFFFFFu - (unsigned)(key & 0xFFFFFFFFull));
  }
}

// ---------------- K3: decode boxes + 80 class scores, one WAVE per row ----------
__global__ __launch_bounds__(256) void k_gather(InPtrs P, const int* sel, float* boxes, float* sv) {
  int wvi = threadIdx.x >> 6;
  int lane = threadIdx.x & 63;
  int wid = blockIdx.x * 4 + wvi;      // grid is exactly BATCH*TOPK/4 blocks
  int b = wid / TOPK;
  int r = wid - b * TOPK;
  __shared__ float s_sc[4][NCLS];

  int a = sel[b * TOPK + r];       // uniform -> broadcast load
  int l = 0;
  while (a >= c_lvoff[l + 1]) ++l;
  int within = a - c_lvoff[l];
  int W = c_lw[l], H = c_lh[l];
  int y = within / W, x = within - y * W;
  int hw = H * W;
  int sp = within;
  float stride = c_ls[l];
  float px = (float)x * stride;
  float py = (float)y * stride;
  float pw = 4.0f * stride;

  const float* shp = P.shp[l];
  float dws = shp[(b * 2 + 0) * hw + sp];
  float dhs = shp[(b * 2 + 1) * hw + sp];
  dws = fminf(fmaxf(dws, -MAX_RATIO_ANCHOR), MAX_RATIO_ANCHOR);
  dhs = fminf(fmaxf(dhs, -MAX_RATIO_ANCHOR), MAX_RATIO_ANCHOR);
  float gw = pw * expf(dws);
  float gh = pw * expf(dhs);
  float ax1 = px - 0.5f * gw, ax2 = px + 0.5f * gw;
  float ay1 = py - 0.5f * gh, ay2 = py + 0.5f * gh;

  const float* bb = P.bbox[l];
  float dx = bb[(b * 4 + 0) * hw + sp];
  float dy = bb[(b * 4 + 1) * hw + sp];
  float dw = bb[(b * 4 + 2) * hw + sp];
  float dh = bb[(b * 4 + 3) * hw + sp];
  dw = fminf(fmaxf(dw, -MAX_RATIO_BBOX), MAX_RATIO_BBOX);
  dh = fminf(fmaxf(dh, -MAX_RATIO_BBOX), MAX_RATIO_BBOX);
  float px2 = (ax1 + ax2) * 0.5f, py2 = (ay1 + ay2) * 0.5f;
  float pw2 = ax2 - ax1, ph2 = ay2 - ay1;
  float gx = px2 + pw2 * dx, gy = py2 + ph2 * dy;
  float gw2 = pw2 * expf(dw), gh2 = ph2 * expf(dh);
  float x1 = fminf(fmaxf(gx - 0.5f * gw2, 0.0f), IMG_WF);
  float x2 = fminf(fmaxf(gx + 0.5f * gw2, 0.0f), IMG_WF);
  float y1 = fminf(fmaxf(gy - 0.5f * gh2, 0.0f), IMG_HF);
  float y2 = fminf(fmaxf(gy + 0.5f * gh2, 0.0f), IMG_HF);
  if (lane == 0) {
    float4 st; st.x = x1; st.y = y1; st.z = x2; st.w = y2;
    ((float4*)boxes)[b * TOPK + r] = st;
  }

  const float* cls = P.cls[l];
  float sl = sigf(P.loc[l][b * hw + sp]);
  bool mask = (sl >= 0.01f);
  int base = (b * NCLS) * hw + sp;
  for (int c = lane; c < NCLS; c += 64) {
    float vv = 0.0f;
    if (mask) {
      float s2 = sigf(sigf(cls[base + c * hw]));
      vv = (s2 > 0.05f) ? s2 : 0.0f;   // SCORE_THR (strict >)
    }
    s_sc[wvi][c] = vv;
  }
  __syncthreads();
  int t = threadIdx.x;
  if (t < NCLS) {
    int r0 = blockIdx.x * 4 - b * TOPK;   // row of wave 0 (TOPK % 4 == 0)
    float4 o; o.x = s_sc[0][t]; o.y = s_sc[1][t]; o.z = s_sc[2][t]; o.w = s_sc[3][t];
    *(float4*)(sv + ((size_t)(b * NCLS + t) * TOPK + r0)) = o;
  }
}

// ---------------- K4: per-(batch,class) greedy NMS, FOUR waves, TWO picks/round --
__global__ __launch_bounds__(256) void k_nms(const float* boxes, const float* sv,
                                             float* keptScore, int* keptRow, int* kc,
                                             const int* flags, const int* gbits, int cap) {
  int bc = blockIdx.x;              // 0..639
  if (flags && flags[bc] == 0) return;   // uniform early-exit (fixup pass)
  int b = bc / NCLS;
  int c = bc - b * NCLS;
  int tid = threadIdx.x;
  int wv = tid >> 6, lane = tid & 63;

  unsigned Glow = 0u;               // low-22 score bits of G; 0 -> no truncation
  if (gbits) Glow = ((unsigned)gbits[b]) & 0x3FFFFFu;

  __shared__ float4 s_box[TOPK];            // 16 KB (offset coords)
  __shared__ float  s_ard[TOPK];            // 4 KB: |val| = area, sign = degenerate
  __shared__ unsigned long long s_p2[2][4]; // parity-buffered per-wave (top1,top2)

  float x1[4], y1[4], x2[4], y2[4], ar[4];
  unsigned key[4];
  float off = (float)c * CLS_OFF;   // exact in f32
  const float* svc = sv + (size_t)(b * NCLS + c) * TOPK;   // class-major: contiguous
  #pragma unroll
  for (int j = 0; j < 4; ++j) {
    int row = j * 256 + tid;
    if (row < TOPK) {
      float4 bo = ((const float4*)boxes)[b * TOPK + row];
      float a = bo.x + off, d = bo.y + off, e = bo.z + off, f = bo.w + off;
      x1[j] = a; y1[j] = d; x2[j] = e; y2[j] = f;
      ar[j] = (e - a) * (f - d);
      unsigned bits = __float_as_uint(svc[row]);   // 0 or in [0x3F000001,0x3F3C0000)
      key[j] = ((bits & 0x3FFFFFu) << 10) | (1023u - (unsigned)row);
      float sden = ar[j] + 1e-6f;
      bool deg = !((double)ar[j] > (double)sden * K2_HALF_UP);
      float4 sb; sb.x = a; sb.y = d; sb.z = e; sb.w = f;
      s_box[row] = sb;
      s_ard[row] = __uint_as_float(__float_as_uint(ar[j]) | (deg ? 0x80000000u : 0u));
    } else {
      x1[j] = y1[j] = x2[j] = y2[j] = ar[j] = 0.0f;
      key[j] = 0u;
    }
  }
  __syncthreads();   // boxes visible

  int kept = 0;
  bool sticky = false;
  float* ks = keptScore + (size_t)(b * NCLS + c) * MAXPER;
  int*   kr = keptRow   + (size_t)(b * NCLS + c) * MAXPER;

  for (int round = 0; round < cap; ++round) {
    int par = round & 1;
    unsigned hi1 = max(key[0], key[1]), lo1 = min(key[0], key[1]);
    unsigned hi2 = max(key[2], key[3]), lo2 = min(key[2], key[3]);
    unsigned m1 = max(hi1, hi2);
    unsigned m2 = max(min(hi1, hi2), max(lo1, lo2));
    unsigned w1, w2;
    wave_red_top2(m1, m2, w1, w2);
    if (lane == 0) s_p2[par][wv] = ((unsigned long long)w1 << 32) | w2;
    __syncthreads();                          // ONE barrier per round
    unsigned k0 = 0u, k1 = 0u;
    #pragma unroll
    for (int w = 0; w < 4; ++w) {
      unsigned long long pp = s_p2[par][w];
      unsigned p1 = (unsigned)(pp >> 32), p2 = (unsigned)pp;
      unsigned tm = min(k0, p1);
      k0 = max(k0, p1);
      k1 = max(tm, max(k1, p2));
    }
    if (k0 < 1024u) break;                    // no live entries
    if ((k0 >> 10) < Glow) break;             // rest of stream < G: outside top-100
    // ---- pick a1 ----
    int brow1 = 1023 - (int)(k0 & 1023u);
    float bs1 = __uint_as_float(0x3F000000u | (k0 >> 10));
    float4 bb1 = s_box[brow1];
    unsigned au1 = __float_as_uint(s_ard[brow1]);
    bool deg1 = (au1 >> 31) != 0u;
    float ba1 = __uint_as_float(au1 & 0x7FFFFFFFu);
    if (tid == 0) { ks[kept] = bs1; kr[kept] = brow1; }
    kept++;
    if (deg1) { sticky = true; break; }       // repeats forever in the ref scan
    if (kept >= cap) break;
    bool live2 = (k1 >= 1024u) && ((k1 >> 10) >= Glow);
    if (!live2) break;
    // ---- try pick a2 (pre-suppression 2nd max) ----
    bool do2 = false, deg2 = false;
    float4 bb2; float ba2 = 0.0f;
    {
      int brow2 = 1023 - (int)(k1 & 1023u);
      float bs2 = __uint_as_float(0x3F000000u | (k1 >> 10));
      bb2 = s_box[brow2];
      unsigned au2 = __float_as_uint(s_ard[brow2]);
      deg2 = (au2 >> 31) != 0u;
      ba2 = __uint_as_float(au2 & 0x7FFFFFFFu);
      float ltx = fmaxf(bb1.x, bb2.x), rbx = fminf(bb1.z, bb2.z);
      float lty = fmaxf(bb1.y, bb2.y), rby = fminf(bb1.w, bb2.w);
      float w_ = fmaxf(rbx - ltx, 0.0f), h_ = fmaxf(rby - lty, 0.0f);
      float inter = w_ * h_;
      float denom = ((ba1 + ba2) - inter) + 1e-6f;
      if (!((double)inter > (double)denom * K2_HALF_UP)) {
        do2 = true;
        if (tid == 0) { ks[kept] = bs2; kr[kept] = brow2; }
        kept++;
      }
    }
    if (do2 && deg2) { sticky = true; break; }
    // ---- suppression: each box vs a1 (and a2 if emitted); OR == sequential ----
    #pragma unroll
    for (int j = 0; j < 4; ++j) {
      {
        float ltx = fmaxf(bb1.x, x1[j]), rbx = fminf(bb1.z, x2[j]);
        float lty = fmaxf(bb1.y, y1[j]), rby = fminf(bb1.w, y2[j]);
        float w_ = fmaxf(rbx - ltx, 0.0f), h_ = fmaxf(rby - lty, 0.0f);
        float inter = w_ * h_;
        float denom = ((ba1 + ar[j]) - inter) + 1e-6f;
        if ((double)inter > (double)denom * K2_HALF_UP) key[j] = 0u;
      }
      if (do2) {
        float ltx = fmaxf(bb2.x, x1[j]), rbx = fminf(bb2.z, x2[j]);
        float lty = fmaxf(bb2.y, y1[j]), rby = fminf(bb2.w, y2[j]);
        float w_ = fmaxf(rbx - ltx, 0.0f), h_ = fmaxf(rby - lty, 0.0f);
        float inter = w_ * h_;
        float denom = ((ba2 + ar[j]) - inter) + 1e-6f;
        if ((double)inter > (double)denom * K2_HALF_UP) key[j] = 0u;
      }
    }
    if (kept >= cap) break;
  }
  if (tid == 0) kc[b * NCLS + c] = sticky ? -kept : kept;
}

// ---------------- K4b: fixup decision + per-batch G ----------------
__global__ __launch_bounds__(256) void k_cut(const float* keptScore, const int* kc,
                                             int* flags, int* gbits) {
  int b = blockIdx.x;
  int tid = threadIdx.x;
  int wv = tid >> 6, lane = tid & 63;
  __shared__ int s_abs[NCLS];
  __shared__ int s_neg[NCLS];
  __shared__ unsigned s_h[2048];
  __shared__ int s_wtot[4];
  __shared__ int s_res[2];
  __shared__ int s_tot[4];

  if (tid < NCLS) {
    int v = kc[b * NCLS + tid];
    s_abs[tid] = (v < 0) ? -v : v;
    s_neg[tid] = (v < 0) ? 1 : 0;
  }
  #pragma unroll
  for (int j = 0; j < 8; ++j) s_h[tid * 8 + j] = 0u;
  __syncthreads();

  unsigned vv[3] = {0u, 0u, 0u};
  #pragma unroll
  for (int t = 0; t < 3; ++t) {
    int e = tid + t * 256;
    if (e < NCLS * CAP) {
      int c = e / CAP, k = e - c * CAP;
      if (k < s_abs[c])
        vv[t] = __float_as_uint(keptScore[(size_t)b * NCLS * MAXPER + c * MAXPER + k])
                & 0x3FFFFFu;
    }
  }
  int live = ((vv[0] != 0u) ? 1 : 0) + ((vv[1] != 0u) ? 1 : 0) + ((vv[2] != 0u) ? 1 : 0);
  live = wave_red_sum_i32(live);
  if (lane == 0) s_tot[wv] = live;
  #pragma unroll
  for (int t = 0; t < 3; ++t) if (vv[t]) atomicAdd(&s_h[vv[t] >> 11], 1u);
  __syncthreads();
  int T = s_tot[0] + s_tot[1] + s_tot[2] + s_tot[3];

  auto scanFind = [&](int target) {
    int base = 2047 - 8 * tid;
    int h[8]; int loc = 0;
    #pragma unroll
    for (int j = 0; j < 8; ++j) { h[j] = (int)s_h[base - j]; loc += h[j]; }
    int incl = loc;
    #pragma unroll
    for (int o = 1; o < 64; o <<= 1) {
      int uu = __shfl_up(incl, o, 64);
      if (lane >= o) incl += uu;
    }
    if (lane == 63) s_wtot[wv] = incl;
    __syncthreads();
    int woff = 0;
    #pragma unroll
    for (int ww = 0; ww < 4; ++ww) woff += (ww < wv) ? s_wtot[ww] : 0;
    int e = woff + incl - loc;
    #pragma unroll
    for (int j = 0; j < 8; ++j) {
      if (e < target && e + h[j] >= target) { s_res[0] = base - j; s_res[1] = e; }
      e += h[j];
    }
    __syncthreads();
  };

  unsigned G = 0u;
  if (T >= MAXPER) {
    scanFind(MAXPER);
    int B1 = s_res[0], NGT1 = s_res[1];
    #pragma unroll
    for (int j = 0; j < 8; ++j) s_h[tid * 8 + j] = 0u;
    __syncthreads();
    #pragma unroll
    for (int t = 0; t < 3; ++t)
      if (vv[t] && (int)(vv[t] >> 11) == B1) atomicAdd(&s_h[vv[t] & 0x7FFu], 1u);
    __syncthreads();
    scanFind(MAXPER - NGT1);
    G = 0x3F000000u | ((unsigned)B1 << 11) | (unsigned)s_res[0];
  }
  if (tid == 0) gbits[b] = (int)G;
  if (tid < NCLS) {
    int f = 0;
    if (s_abs[tid] == CAP && !s_neg[tid]) {
      unsigned slast = __float_as_uint(
          keptScore[(size_t)b * NCLS * MAXPER + tid * MAXPER + (CAP - 1)]);
      if (slast >= G) f = 1;   // scores > 0.5: bit compare == float compare
    }
    flags[b * NCLS + tid] = f;
  }
}

// ---------------- K5: sort-based merge -> top-100 (rank-by-count) ----------------
__global__ __launch_bounds__(256) void k_merge(const float* boxes, const float* keptScore,
                                               const int* keptRow, const int* kc, float* out) {
  int b = blockIdx.x;
  int tid = threadIdx.x;
  int wv = tid >> 6, lane = tid & 63;
  __shared__ int s_kc[NCLS];
  __shared__ unsigned s_h[2048];
  __shared__ int s_wtot[4];
  __shared__ int s_res[2];
  __shared__ int s_tot[4];
  __shared__ int s_pos;
  __shared__ int s_sticky;
  __shared__ int s_navail;
  __shared__ unsigned long long s_pool[POOL];     // 2 KB
  __shared__ unsigned long long s_sorted[POOL];   // 2 KB

  for (int c = tid; c < NCLS; c += 256) s_kc[c] = kc[b * NCLS + c];
  if (tid == 0) { s_pos = 0; s_sticky = 0x7FFFFFFF; s_navail = 0; }
  for (int i = tid; i < POOL; i += 256) { s_pool[i] = 0ull; s_sorted[i] = 0ull; }
  #pragma unroll
  for (int j = 0; j < 8; ++j) s_h[tid * 8 + j] = 0u;
  __syncthreads();

  unsigned sc[32];
  #pragma unroll
  for (int s = 0; s < 32; ++s) {
    int i = tid + s * 256;
    unsigned vvv = 0u;
    if (i < NCLS * MAXPER) {
      int c = i / MAXPER, k = i - c * MAXPER;
      int kcv = s_kc[c];
      int ka = (kcv < 0) ? -kcv : kcv;
      if (k < ka)
        vvv = __float_as_uint(keptScore[(size_t)b * NCLS * MAXPER + i]) & 0x3FFFFFu;
    }
    sc[s] = vvv;
  }
  int live = 0;
  #pragma unroll
  for (int s = 0; s < 32; ++s) live += (sc[s] != 0u) ? 1 : 0;
  live = wave_red_sum_i32(live);
  if (lane == 0) s_tot[wv] = live;
  #pragma unroll
  for (int s = 0; s < 32; ++s) if (sc[s]) atomicAdd(&s_h[sc[s] >> 11], 1u);
  __syncthreads();
  int T = s_tot[0] + s_tot[1] + s_tot[2] + s_tot[3];   // total stream entries

  auto scanFind = [&](int target) {
    int base = 2047 - 8 * tid;
    int h[8]; int loc = 0;
    #pragma unroll
    for (int j = 0; j < 8; ++j) { h[j] = (int)s_h[base - j]; loc += h[j]; }
    int incl = loc;
    #pragma unroll
    for (int o = 1; o < 64; o <<= 1) {
      int uu = __shfl_up(incl, o, 64);
      if (lane >= o) incl += uu;
    }
    if (lane == 63) s_wtot[wv] = incl;
    __syncthreads();
    int woff = 0;
    #pragma unroll
    for (int ww = 0; ww < 4; ++ww) woff += (ww < wv) ? s_wtot[ww] : 0;
    int e = woff + incl - loc;
    #pragma unroll
    for (int j = 0; j < 8; ++j) {
      if (e < target && e + h[j] >= target) { s_res[0] = base - j; s_res[1] = e; }
      e += h[j];
    }
    __syncthreads();
  };

  unsigned V = 1u;                     // all live if T <= 100
  if (T > MAXPER) {
    scanFind(MAXPER);
    int B1 = s_res[0], NGT1 = s_res[1];
    #pragma unroll
    for (int j = 0; j < 8; ++j) s_h[tid * 8 + j] = 0u;
    __syncthreads();
    #pragma unroll
    for (int s = 0; s < 32; ++s)
      if (sc[s] && (int)(sc[s] >> 11) == B1) atomicAdd(&s_h[sc[s] & 0x7FFu], 1u);
    __syncthreads();
    scanFind(MAXPER - NGT1);
    V = ((unsigned)B1 << 11) | (unsigned)s_res[0];   // count(>=V)>=100, count(>V)<100
  }

  #pragma unroll
  for (int s = 0; s < 32; ++s) {
    if (sc[s] >= V && sc[s] != 0u) {
      int i = tid + s * 256;
      int c = i / MAXPER, k = i - c * MAXPER;
      int kcv = s_kc[c];
      int ka = (kcv < 0) ? -kcv : kcv;
      unsigned st = (kcv < 0 && k == ka - 1) ? 1u : 0u;
      unsigned row = (unsigned)keptRow[(size_t)b * NCLS * MAXPER + i];
      unsigned flat = row * 80u + (unsigned)c;
      int p = atomicAdd(&s_pos, 1);
      if (p < POOL)
        s_pool[p] = ((unsigned long long)(0x3F000000u | sc[s]) << 32) |
                    (unsigned long long)(0x7FFFFFFFu - ((flat << 1) | st));
    }
  }
  __syncthreads();

  if (tid < POOL) {
    unsigned long long mykey = s_pool[tid];
    if (mykey != 0ull) {
      int rank = 0;
      #pragma unroll 8
      for (int s = 0; s < POOL; ++s) rank += (s_pool[s] > mykey) ? 1 : 0;
      s_sorted[rank] = mykey;
    }
  }
  __syncthreads();

  if (tid < MAXPER) {
    unsigned long long key = s_sorted[tid];
    if (key != 0ull) {
      atomicAdd(&s_navail, 1);
      if ((((unsigned)key) & 1u) == 0u) atomicMin(&s_sticky, tid);  // low bit 0 <=> sticky
    }
  }
  __syncthreads();
  int navail = s_navail;
  int p = s_sticky;
  int n = (p < navail) ? MAXPER : navail;

  if (tid == 0) out[b] = (float)n;
  const int OB = BATCH;                    // 8
  const int OP = OB + BATCH * MAXPER * 4;  // 3208
  const int OS = OP + BATCH * MAXPER;      // 4008
  if (tid < MAXPER) {
    int k = tid;
    float bx0 = 0.f, bx1 = 0.f, bx2 = 0.f, bx3 = 0.f, scf = 0.f, cf = -1.0f;
    if (k < n) {
      int idx = (k > p) ? p : k;           // p == INT_MAX when no sticky -> idx = k
      unsigned long long key = s_sorted[idx];
      unsigned flat = (0x7FFFFFFFu - (unsigned)key) >> 1;
      unsigned cls = flat % 80u;
      unsigned row = flat / 80u;
      float4 bo = ((const float4*)boxes)[b * TOPK + row];
      bx0 = bo.x; bx1 = bo.y; bx2 = bo.z; bx3 = bo.w;
      scf = __uint_as_float((unsigned)(key >> 32));
      cf = (float)cls;
    }
    float* po = out + OB + (size_t)(b * MAXPER + k) * 4;
    po[0] = bx0; po[1] = bx1; po[2] = bx2; po[3] = bx3;
    out[OP + b * MAXPER + k] = scf;
    out[OS + b * MAXPER + k] = cf;
  }
}

extern "C" void kernel_launch(void* const* d_in, const int* in_sizes, int n_in,
                              void* d_out, int out_size, void* d_ws, size_t ws_size,
                              hipStream_t stream) {
  InPtrs P;
  for (int l = 0; l < 5; ++l) {
    P.cls[l]  = (const float*)d_in[4 * l + 0];
    P.bbox[l] = (const float*)d_in[4 * l + 1];
    P.shp[l]  = (const float*)d_in[4 * l + 2];
    P.loc[l]  = (const float*)d_in[4 * l + 3];
  }
  float* maxscore  = (float*)d_ws;                          // B*NA
  int*   sel       = (int*)(maxscore + BATCH * NA);         // B*TOPK
  float* boxes     = (float*)(sel + BATCH * TOPK);          // B*TOPK*4 (16B aligned)
  float* sv        = boxes + BATCH * TOPK * 4;              // B*80*TOPK (class-major)
  float* keptScore = sv + BATCH * NCLS * TOPK;              // B*80*100
  int*   keptRow   = (int*)(keptScore + BATCH * NCLS * MAXPER);
  int*   kc        = keptRow + BATCH * NCLS * MAXPER;
  int*   flags     = kc + BATCH * NCLS;
  int*   gbits     = flags + BATCH * NCLS;                  // per-batch G bit pattern
  float* out = (float*)d_out;

  k_maxscore<<<(BATCH * (NA / 4) * 4 + 255) / 256, 256, 0, stream>>>(P, maxscore);
  k_select<<<BATCH, 1024, 0, stream>>>(maxscore, sel);
  k_gather<<<BATCH * TOPK / 4, 256, 0, stream>>>(P, sel, boxes, sv);
  k_nms<<<BATCH * NCLS, 256, 0, stream>>>(boxes, sv, keptScore, keptRow, kc,
                                          (const int*)nullptr, (const int*)nullptr, CAP);
  k_cut<<<BATCH, 256, 0, stream>>>(keptScore, kc, flags, gbits);
  k_nms<<<BATCH * NCLS, 256, 0, stream>>>(boxes, sv, keptScore, keptRow, kc,
                                          flags, gbits, MAXPER);
  k_merge<<<BATCH, 256, 0, stream>>>(boxes, keptScore, keptRow, kc, out);
}

// Round 10
// 187.199 us; speedup vs baseline: 3.1103x; 1.0401x over previous
//
#include <hip/hip_runtime.h>
#include <stdint.h>

#define NCLS 80
#define BATCH 8
#define NA 20460          // total anchors per image across 5 levels
#define TOPK 1000
#define MAXPER 100
#define CAP 8             // capped per-class NMS depth (exact fixup via flags)
#define POOL 256          // merge candidate pool (top-100 + tie slack)
#define IMG_WF 1280.0f
#define IMG_HF 768.0f
#define CLS_OFF 4096.0f
#define MAX_RATIO_ANCHOR 13.815510557964274f  // |log(1e-6)|
#define MAX_RATIO_BBOX   4.1351665567423557f  // |log(16/1000)|

// RN(a/b) > 0.5  <=>  a > b*(0.5 + 2^-25) as reals (0.5 mantissa even, tie->down).
// b has 24-bit mantissa, K2 has 25 -> product exact in f64; comparison exact.
#define K2_HALF_UP (0.5 + 0x1p-25)

__constant__ int   c_lvoff[6]  = {0, 15360, 19200, 20160, 20400, 20460};
__constant__ int   c_lvoff4[6] = {0, 3840, 4800, 5040, 5100, 5115};   // /4
__constant__ int   c_lw[5]    = {160, 80, 40, 20, 10};
__constant__ int   c_lh[5]    = {96, 48, 24, 12, 6};
__constant__ float c_ls[5]    = {8.f, 16.f, 32.f, 64.f, 128.f};

struct InPtrs {
  const float* cls[5];
  const float* bbox[5];
  const float* shp[5];
  const float* loc[5];
};

__device__ __forceinline__ float sigf(float x) { return 1.0f / (1.0f + expf(-x)); }

// ---- DPP wave64 reductions (VALU-only) ----
__device__ __forceinline__ int wave_red_sum_i32(int v) {
  int t;
  t = __builtin_amdgcn_update_dpp(0, v, 0x111, 0xf, 0xf, false); v += t;
  t = __builtin_amdgcn_update_dpp(0, v, 0x112, 0xf, 0xf, false); v += t;
  t = __builtin_amdgcn_update_dpp(0, v, 0x114, 0xf, 0xf, false); v += t;
  t = __builtin_amdgcn_update_dpp(0, v, 0x118, 0xf, 0xf, false); v += t;
  t = __builtin_amdgcn_update_dpp(0, v, 0x142, 0xf, 0xf, false); v += t;
  t = __builtin_amdgcn_update_dpp(0, v, 0x143, 0xf, 0xf, false); v += t;
  return __builtin_amdgcn_readlane(v, 63);
}
// top-2 of the wave's values: merge over disjoint sets; exact.
__device__ __forceinline__ void wave_red_top2(unsigned m1, unsigned m2,
                                              unsigned& r1, unsigned& r2) {
#define T2STEP(ctrl) { \
    unsigned o1 = (unsigned)__builtin_amdgcn_update_dpp(0, (int)m1, ctrl, 0xf, 0xf, false); \
    unsigned o2 = (unsigned)__builtin_amdgcn_update_dpp(0, (int)m2, ctrl, 0xf, 0xf, false); \
    unsigned tm = min(m1, o1); \
    m1 = max(m1, o1); \
    m2 = max(tm, max(m2, o2)); }
  T2STEP(0x111) T2STEP(0x112) T2STEP(0x114) T2STEP(0x118) T2STEP(0x142) T2STEP(0x143)
#undef T2STEP
  r1 = (unsigned)__builtin_amdgcn_readlane((int)m1, 63);
  r2 = (unsigned)__builtin_amdgcn_readlane((int)m2, 63);
}

// ---------------- K1: per-anchor max score, 4-way class split + shfl combine ----
// 640 blocks: lanes 4p..4p+3 each reduce 20 classes of anchor-quad p, combine
// via two xor-max steps (max is grouping-exact), lane h=0 applies loc mask +
// double sigmoid and writes. [round-8: 203.6 -> 194.7 with this k_maxscore]
__global__ __launch_bounds__(256) void k_maxscore(InPtrs P, float* maxscore) {
  int gid = blockIdx.x * 256 + threadIdx.x;
  int p = gid >> 2;                    // anchor-quad id
  int h = gid & 3;                     // class chunk: [20h, 20h+20)
  if (p >= BATCH * (NA / 4)) return;   // tail groups of 4 are wholly inactive
  int b = p / (NA / 4);
  int q = p - b * (NA / 4);            // float4 index within batch (level-merged)
  int l = 0;
  while (q >= c_lvoff4[l + 1]) ++l;
  int hw = c_lh[l] * c_lw[l];
  int sp = (q - c_lvoff4[l]) * 4;
  const float4* cls = (const float4*)(P.cls[l] + (size_t)(b * NCLS + h * 20) * hw + sp);
  int s4 = hw >> 2;                    // class stride in float4 units
  float4 m = cls[0];
  for (int c = 1; c < NCLS / 4; ++c) {
    float4 v = cls[(size_t)c * s4];
    m.x = fmaxf(m.x, v.x); m.y = fmaxf(m.y, v.y);
    m.z = fmaxf(m.z, v.z); m.w = fmaxf(m.w, v.w);
  }
  #pragma unroll
  for (int o = 1; o < 4; o <<= 1) {    // combine 4 chunks within the lane quad
    m.x = fmaxf(m.x, __shfl_xor(m.x, o, 64));
    m.y = fmaxf(m.y, __shfl_xor(m.y, o, 64));
    m.z = fmaxf(m.z, __shfl_xor(m.z, o, 64));
    m.w = fmaxf(m.w, __shfl_xor(m.w, o, 64));
  }
  if (h == 0) {
    float4 lo = *(const float4*)(P.loc[l] + (size_t)b * hw + sp);
    float4 r;
    r.x = (sigf(lo.x) >= 0.01f) ? sigf(sigf(m.x)) : 0.0f;  // monotone: max commutes
    r.y = (sigf(lo.y) >= 0.01f) ? sigf(sigf(m.y)) : 0.0f;
    r.z = (sigf(lo.z) >= 0.01f) ? sigf(sigf(m.z)) : 0.0f;
    r.w = (sigf(lo.w) >= 0.01f) ? sigf(sigf(m.w)) : 0.0f;
    ((float4*)maxscore)[(size_t)b * (NA / 4) + q] = r;
  }
}

// ---------------- K2: exact top-1000 per batch, in top_k order ----------------
// Two-level 2048-bucket LDS radix histogram + shfl suffix-scan (empirically the
// fastest variant). One-scan collect of >V, ==V fill ascending, hybrid bitonic.
__global__ __launch_bounds__(1024) void k_select(const float* maxscore, int* sel) {
  int b = blockIdx.x;
  const unsigned int* ms = (const unsigned int*)(maxscore + (size_t)b * NA);
  int tid = threadIdx.x;
  int wv = tid >> 6;
  int lane = tid & 63;
  __shared__ unsigned s_h[2048];      // level-1 then level-2 histogram (8 KB)
  __shared__ int s_wtot[16];
  __shared__ int s_res[2];            // {bucket, count-above} from scanFind
  __shared__ unsigned long long s_A[1024];
  __shared__ unsigned long long s_B[1024];

  // contiguous per-thread layout: thread t owns elements [20t, 20t+20)
  unsigned w[20];
  #pragma unroll
  for (int k = 0; k < 5; ++k) {
    int q = tid * 5 + k;
    uint4 u = (q < NA / 4) ? ((const uint4*)ms)[q] : make_uint4(0u, 0u, 0u, 0u);
    w[k * 4 + 0] = u.x & 0x3FFFFFu;
    w[k * 4 + 1] = u.y & 0x3FFFFFu;
    w[k * 4 + 2] = u.z & 0x3FFFFFu;
    w[k * 4 + 3] = u.w & 0x3FFFFFu;
  }
  int lim = NA - tid * 20;            // valid element count for this thread
  lim = (lim < 0) ? 0 : ((lim > 20) ? 20 : lim);

  s_h[tid] = 0u; s_h[tid + 1024] = 0u;
  __syncthreads();

  // descending-order crossing: unique bucket B with cntAbove(B) < target <= cntAbove(B)+h[B]
  auto scanFind = [&](int target) {
    int b0 = 2047 - 2 * tid;          // thread t owns descending positions 2t, 2t+1
    int h0 = (int)s_h[b0];
    int h1 = (int)s_h[b0 - 1];
    int pair = h0 + h1;
    int incl = pair;
    #pragma unroll
    for (int o = 1; o < 64; o <<= 1) {
      int uu = __shfl_up(incl, o, 64);
      if (lane >= o) incl += uu;
    }
    if (lane == 63) s_wtot[wv] = incl;
    __syncthreads();
    int woff = 0;
    #pragma unroll
    for (int ww = 0; ww < 16; ++ww) woff += (ww < wv) ? s_wtot[ww] : 0;
    int excl = woff + incl - pair;    // count in buckets strictly above b0
    if (excl < target && excl + h0 >= target) { s_res[0] = b0; s_res[1] = excl; }
    int e1 = excl + h0;
    if (e1 < target && e1 + h1 >= target) { s_res[0] = b0 - 1; s_res[1] = e1; }
    __syncthreads();
  };

  // ---- level 1: bucket = w >> 11 ----
  #pragma unroll
  for (int k = 0; k < 20; ++k) atomicAdd(&s_h[w[k] >> 11], 1u);
  __syncthreads();
  scanFind(TOPK);
  int B1 = s_res[0];
  int NGT1 = s_res[1];                // count of keys in buckets > B1 (< 1000)

  // ---- level 2: low 11 bits within bucket B1 ----
  s_h[tid] = 0u; s_h[tid + 1024] = 0u;
  __syncthreads();
  #pragma unroll
  for (int k = 0; k < 20; ++k)
    if ((int)(w[k] >> 11) == B1) atomicAdd(&s_h[w[k] & 0x7FFu], 1u);
  __syncthreads();
  scanFind(TOPK - NGT1);
  unsigned V = ((unsigned)B1 << 11) | (unsigned)s_res[0];  // exact 1000th key

  if (tid < 1024 - TOPK) s_A[TOPK + tid] = 0ull;  // pad slots (sink in desc sort)

  // ---- collect >V via ONE block prefix-scan (slot order arbitrary; bitonic sorts) ----
  int cgt = 0;
  #pragma unroll
  for (int k = 0; k < 20; ++k) cgt += (w[k] > V) ? 1 : 0;   // OOB w=0, never >V
  {
    int incl = cgt;
    #pragma unroll
    for (int o = 1; o < 64; o <<= 1) {
      int uu = __shfl_up(incl, o, 64);
      if (lane >= o) incl += uu;
    }
    if (lane == 63) s_wtot[wv] = incl;
    __syncthreads();
    int woff = 0, tot = 0;
    #pragma unroll
    for (int ww = 0; ww < 16; ++ww) { tot += s_wtot[ww]; woff += (ww < wv) ? s_wtot[ww] : 0; }
    int pos = woff + incl - cgt;
    #pragma unroll
    for (int k = 0; k < 20; ++k) {
      if (w[k] > V) {
        int i = tid * 20 + k;
        s_A[pos++] = ((unsigned long long)w[k] << 32) |
                     (unsigned long long)(0xFFFFFFFFu - (unsigned)i);
      }
    }
    int ngt = tot;
    int need = TOPK - ngt;            // >= 1; filled by ==V in ascending index order
    __syncthreads();                  // s_wtot reuse hazard fence

    // ---- ==V fill in ascending index order (from registers, contiguous layout) ----
    int ceq = 0;
    #pragma unroll
    for (int k = 0; k < 20; ++k) if (k < lim && w[k] == V) ++ceq;
    int incl2 = ceq;
    #pragma unroll
    for (int o = 1; o < 64; o <<= 1) {
      int uu = __shfl_up(incl2, o, 64);
      if (lane >= o) incl2 += uu;
    }
    if (lane == 63) s_wtot[wv] = incl2;
    __syncthreads();
    int woff2 = 0;
    #pragma unroll
    for (int ww = 0; ww < 16; ++ww) woff2 += (ww < wv) ? s_wtot[ww] : 0;
    int r = woff2 + incl2 - ceq;      // global exclusive prefix (index order)
    #pragma unroll
    for (int k = 0; k < 20; ++k) {
      if (k < lim && w[k] == V) {
        if (r < need) {
          int i = tid * 20 + k;
          s_A[ngt + r] = ((unsigned long long)V << 32) |
                         (unsigned long long)(0xFFFFFFFFu - (unsigned)i);
        }
        ++r;
      }
    }
  }
  __syncthreads();

  // hybrid bitonic sort, descending, one key/thread in registers.
  unsigned long long key = s_A[tid];
  int tog = 0;   // 0 -> s_B first (s_A holds live data at entry)
  for (unsigned k = 2; k <= 1024; k <<= 1) {
    for (unsigned j = k >> 1; j > 0; j >>= 1) {
      unsigned long long other;
      if (j >= 64) {
        unsigned long long* cur = tog ? s_A : s_B;
        cur[tid] = key;
        __syncthreads();
        other = cur[tid ^ (int)j];
        tog ^= 1;
      } else {
        other = __shfl_xor(key, (int)j, 64);
      }
      bool takeMax = (((tid & (int)k) == 0) == ((tid & (int)j) == 0));
      unsigned long long mx = (key > other) ? key : other;
      unsigned long long mn = (key > other) ? other : key;
      key = takeMax ? mx : mn;
    }
  }
  if (tid < TOPK) {
    sel[b * TOPK + tid] = (int)(0xFFFFFFFFu - (unsigned)(key & 0xFFFFFFFFull));
  }
}

// ---------------- K3: decode boxes + 80 class scores, one WAVE per row ----------
__global__ __launch_bounds__(256) void k_gather(InPtrs P, const int* sel, float* boxes, float* sv) {
  int wvi = threadIdx.x >> 6;
  int lane = threadIdx.x & 63;
  int wid = blockIdx.x * 4 + wvi;      // grid is exactly BATCH*TOPK/4 blocks
  int b = wid / TOPK;
  int r = wid - b * TOPK;
  __shared__ float s_sc[4][NCLS];

  int a = sel[b * TOPK + r];       // uniform -> broadcast load
  int l = 0;
  while (a >= c_lvoff[l + 1]) ++l;
  int within = a - c_lvoff[l];
  int W = c_lw[l], H = c_lh[l];
  int y = within / W, x = within - y * W;
  int hw = H * W;
  int sp = within;
  float stride = c_ls[l];
  float px = (float)x * stride;
  float py = (float)y * stride;
  float pw = 4.0f * stride;

  const float* shp = P.shp[l];
  float dws = shp[(b * 2 + 0) * hw + sp];
  float dhs = shp[(b * 2 + 1) * hw + sp];
  dws = fminf(fmaxf(dws, -MAX_RATIO_ANCHOR), MAX_RATIO_ANCHOR);
  dhs = fminf(fmaxf(dhs, -MAX_RATIO_ANCHOR), MAX_RATIO_ANCHOR);
  float gw = pw * expf(dws);
  float gh = pw * expf(dhs);
  float ax1 = px - 0.5f * gw, ax2 = px + 0.5f * gw;
  float ay1 = py - 0.5f * gh, ay2 = py + 0.5f * gh;

  const float* bb = P.bbox[l];
  float dx = bb[(b * 4 + 0) * hw + sp];
  float dy = bb[(b * 4 + 1) * hw + sp];
  float dw = bb[(b * 4 + 2) * hw + sp];
  float dh = bb[(b * 4 + 3) * hw + sp];
  dw = fminf(fmaxf(dw, -MAX_RATIO_BBOX), MAX_RATIO_BBOX);
  dh = fminf(fmaxf(dh, -MAX_RATIO_BBOX), MAX_RATIO_BBOX);
  float px2 = (ax1 + ax2) * 0.5f, py2 = (ay1 + ay2) * 0.5f;
  float pw2 = ax2 - ax1, ph2 = ay2 - ay1;
  float gx = px2 + pw2 * dx, gy = py2 + ph2 * dy;
  float gw2 = pw2 * expf(dw), gh2 = ph2 * expf(dh);
  float x1 = fminf(fmaxf(gx - 0.5f * gw2, 0.0f), IMG_WF);
  float x2 = fminf(fmaxf(gx + 0.5f * gw2, 0.0f), IMG_WF);
  float y1 = fminf(fmaxf(gy - 0.5f * gh2, 0.0f), IMG_HF);
  float y2 = fminf(fmaxf(gy + 0.5f * gh2, 0.0f), IMG_HF);
  if (lane == 0) {
    float4 st; st.x = x1; st.y = y1; st.z = x2; st.w = y2;
    ((float4*)boxes)[b * TOPK + r] = st;
  }

  const float* cls = P.cls[l];
  float sl = sigf(P.loc[l][b * hw + sp]);
  bool mask = (sl >= 0.01f);
  int base = (b * NCLS) * hw + sp;
  for (int c = lane; c < NCLS; c += 64) {
    float vv = 0.0f;
    if (mask) {
      float s2 = sigf(sigf(cls[base + c * hw]));
      vv = (s2 > 0.05f) ? s2 : 0.0f;   // SCORE_THR (strict >)
    }
    s_sc[wvi][c] = vv;
  }
  __syncthreads();
  int t = threadIdx.x;
  if (t < NCLS) {
    int r0 = blockIdx.x * 4 - b * TOPK;   // row of wave 0 (TOPK % 4 == 0)
    float4 o; o.x = s_sc[0][t]; o.y = s_sc[1][t]; o.z = s_sc[2][t]; o.w = s_sc[3][t];
    *(float4*)(sv + ((size_t)(b * NCLS + t) * TOPK + r0)) = o;
  }
}

// ---------------- K4: per-(batch,class) greedy NMS, FOUR waves, TWO picks/round --
__global__ __launch_bounds__(256) void k_nms(const float* boxes, const float* sv,
                                             float* keptScore, int* keptRow, int* kc,
                                             const int* flags, const int* gbits, int cap) {
  int bc = blockIdx.x;              // 0..639
  if (flags && flags[bc] == 0) return;   // uniform early-exit (fixup pass)
  int b = bc / NCLS;
  int c = bc - b * NCLS;
  int tid = threadIdx.x;
  int wv = tid >> 6, lane = tid & 63;

  unsigned Glow = 0u;               // low-22 score bits of G; 0 -> no truncation
  if (gbits) Glow = ((unsigned)gbits[b]) & 0x3FFFFFu;

  __shared__ float4 s_box[TOPK];            // 16 KB (offset coords)
  __shared__ float  s_ard[TOPK];            // 4 KB: |val| = area, sign = degenerate
  __shared__ unsigned long long s_p2[2][4]; // parity-buffered per-wave (top1,top2)

  float x1[4], y1[4], x2[4], y2[4], ar[4];
  unsigned key[4];
  float off = (float)c * CLS_OFF;   // exact in f32
  const float* svc = sv + (size_t)(b * NCLS + c) * TOPK;   // class-major: contiguous
  #pragma unroll
  for (int j = 0; j < 4; ++j) {
    int row = j * 256 + tid;
    if (row < TOPK) {
      float4 bo = ((const float4*)boxes)[b * TOPK + row];
      float a = bo.x + off, d = bo.y + off, e = bo.z + off, f = bo.w + off;
      x1[j] = a; y1[j] = d; x2[j] = e; y2[j] = f;
      ar[j] = (e - a) * (f - d);
      unsigned bits = __float_as_uint(svc[row]);   // 0 or in [0x3F000001,0x3F3C0000)
      key[j] = ((bits & 0x3FFFFFu) << 10) | (1023u - (unsigned)row);
      float sden = ar[j] + 1e-6f;
      bool deg = !((double)ar[j] > (double)sden * K2_HALF_UP);
      float4 sb; sb.x = a; sb.y = d; sb.z = e; sb.w = f;
      s_box[row] = sb;
      s_ard[row] = __uint_as_float(__float_as_uint(ar[j]) | (deg ? 0x80000000u : 0u));
    } else {
      x1[j] = y1[j] = x2[j] = y2[j] = ar[j] = 0.0f;
      key[j] = 0u;
    }
  }
  __syncthreads();   // boxes visible

  int kept = 0;
  bool sticky = false;
  float* ks = keptScore + (size_t)(b * NCLS + c) * MAXPER;
  int*   kr = keptRow   + (size_t)(b * NCLS + c) * MAXPER;

  for (int round = 0; round < cap; ++round) {
    int par = round & 1;
    unsigned hi1 = max(key[0], key[1]), lo1 = min(key[0], key[1]);
    unsigned hi2 = max(key[2], key[3]), lo2 = min(key[2], key[3]);
    unsigned m1 = max(hi1, hi2);
    unsigned m2 = max(min(hi1, hi2), max(lo1, lo2));
    unsigned w1, w2;
    wave_red_top2(m1, m2, w1, w2);
    if (lane == 0) s_p2[par][wv] = ((unsigned long long)w1 << 32) | w2;
    __syncthreads();                          // ONE barrier per round
    unsigned k0 = 0u, k1 = 0u;
    #pragma unroll
    for (int w = 0; w < 4; ++w) {
      unsigned long long pp = s_p2[par][w];
      unsigned p1 = (unsigned)(pp >> 32), p2 = (unsigned)pp;
      unsigned tm = min(k0, p1);
      k0 = max(k0, p1);
      k1 = max(tm, max(k1, p2));
    }
    if (k0 < 1024u) break;                    // no live entries
    if ((k0 >> 10) < Glow) break;             // rest of stream < G: outside top-100
    // ---- pick a1 ----
    int brow1 = 1023 - (int)(k0 & 1023u);
    float bs1 = __uint_as_float(0x3F000000u | (k0 >> 10));
    float4 bb1 = s_box[brow1];
    unsigned au1 = __float_as_uint(s_ard[brow1]);
    bool deg1 = (au1 >> 31) != 0u;
    float ba1 = __uint_as_float(au1 & 0x7FFFFFFFu);
    if (tid == 0) { ks[kept] = bs1; kr[kept] = brow1; }
    kept++;
    if (deg1) { sticky = true; break; }       // repeats forever in the ref scan
    if (kept >= cap) break;
    bool live2 = (k1 >= 1024u) && ((k1 >> 10) >= Glow);
    if (!live2) break;
    // ---- try pick a2 (pre-suppression 2nd max) ----
    bool do2 = false, deg2 = false;
    float4 bb2; float ba2 = 0.0f;
    {
      int brow2 = 1023 - (int)(k1 & 1023u);
      float bs2 = __uint_as_float(0x3F000000u | (k1 >> 10));
      bb2 = s_box[brow2];
      unsigned au2 = __float_as_uint(s_ard[brow2]);
      deg2 = (au2 >> 31) != 0u;
      ba2 = __uint_as_float(au2 & 0x7FFFFFFFu);
      float ltx = fmaxf(bb1.x, bb2.x), rbx = fminf(bb1.z, bb2.z);
      float lty = fmaxf(bb1.y, bb2.y), rby = fminf(bb1.w, bb2.w);
      float w_ = fmaxf(rbx - ltx, 0.0f), h_ = fmaxf(rby - lty, 0.0f);
      float inter = w_ * h_;
      float denom = ((ba1 + ba2) - inter) + 1e-6f;
      if (!((double)inter > (double)denom * K2_HALF_UP)) {
        do2 = true;
        if (tid == 0) { ks[kept] = bs2; kr[kept] = brow2; }
        kept++;
      }
    }
    if (do2 && deg2) { sticky = true; break; }
    // ---- suppression: each box vs a1 (and a2 if emitted); OR == sequential ----
    #pragma unroll
    for (int j = 0; j < 4; ++j) {
      {
        float ltx = fmaxf(bb1.x, x1[j]), rbx = fminf(bb1.z, x2[j]);
        float lty = fmaxf(bb1.y, y1[j]), rby = fminf(bb1.w, y2[j]);
        float w_ = fmaxf(rbx - ltx, 0.0f), h_ = fmaxf(rby - lty, 0.0f);
        float inter = w_ * h_;
        float denom = ((ba1 + ar[j]) - inter) + 1e-6f;
        if ((double)inter > (double)denom * K2_HALF_UP) key[j] = 0u;
      }
      if (do2) {
        float ltx = fmaxf(bb2.x, x1[j]), rbx = fminf(bb2.z, x2[j]);
        float lty = fmaxf(bb2.y, y1[j]), rby = fminf(bb2.w, y2[j]);
        float w_ = fmaxf(rbx - ltx, 0.0f), h_ = fmaxf(rby - lty, 0.0f);
        float inter = w_ * h_;
        float denom = ((ba2 + ar[j]) - inter) + 1e-6f;
        if ((double)inter > (double)denom * K2_HALF_UP) key[j] = 0u;
      }
    }
    if (kept >= cap) break;
  }
  if (tid == 0) kc[b * NCLS + c] = sticky ? -kept : kept;
}

// ---------------- K4b: fixup decision + per-batch G ----------------
__global__ __launch_bounds__(256) void k_cut(const float* keptScore, const int* kc,
                                             int* flags, int* gbits) {
  int b = blockIdx.x;
  int tid = threadIdx.x;
  int wv = tid >> 6, lane = tid & 63;
  __shared__ int s_abs[NCLS];
  __shared__ int s_neg[NCLS];
  __shared__ unsigned s_h[2048];
  __shared__ int s_wtot[4];
  __shared__ int s_res[2];
  __shared__ int s_tot[4];

  if (tid < NCLS) {
    int v = kc[b * NCLS + tid];
    s_abs[tid] = (v < 0) ? -v : v;
    s_neg[tid] = (v < 0) ? 1 : 0;
  }
  #pragma unroll
  for (int j = 0; j < 8; ++j) s_h[tid * 8 + j] = 0u;
  __syncthreads();

  unsigned vv[3] = {0u, 0u, 0u};
  #pragma unroll
  for (int t = 0; t < 3; ++t) {
    int e = tid + t * 256;
    if (e < NCLS * CAP) {
      int c = e / CAP, k = e - c * CAP;
      if (k < s_abs[c])
        vv[t] = __float_as_uint(keptScore[(size_t)b * NCLS * MAXPER + c * MAXPER + k])
                & 0x3FFFFFu;
    }
  }
  int live = ((vv[0] != 0u) ? 1 : 0) + ((vv[1] != 0u) ? 1 : 0) + ((vv[2] != 0u) ? 1 : 0);
  live = wave_red_sum_i32(live);
  if (lane == 0) s_tot[wv] = live;
  #pragma unroll
  for (int t = 0; t < 3; ++t) if (vv[t]) atomicAdd(&s_h[vv[t] >> 11], 1u);
  __syncthreads();
  int T = s_tot[0] + s_tot[1] + s_tot[2] + s_tot[3];

  auto scanFind = [&](int target) {
    int base = 2047 - 8 * tid;
    int h[8]; int loc = 0;
    #pragma unroll
    for (int j = 0; j < 8; ++j) { h[j] = (int)s_h[base - j]; loc += h[j]; }
    int incl = loc;
    #pragma unroll
    for (int o = 1; o < 64; o <<= 1) {
      int uu = __shfl_up(incl, o, 64);
      if (lane >= o) incl += uu;
    }
    if (lane == 63) s_wtot[wv] = incl;
    __syncthreads();
    int woff = 0;
    #pragma unroll
    for (int ww = 0; ww < 4; ++ww) woff += (ww < wv) ? s_wtot[ww] : 0;
    int e = woff + incl - loc;
    #pragma unroll
    for (int j = 0; j < 8; ++j) {
      if (e < target && e + h[j] >= target) { s_res[0] = base - j; s_res[1] = e; }
      e += h[j];
    }
    __syncthreads();
  };

  unsigned G = 0u;
  if (T >= MAXPER) {
    scanFind(MAXPER);
    int B1 = s_res[0], NGT1 = s_res[1];
    #pragma unroll
    for (int j = 0; j < 8; ++j) s_h[tid * 8 + j] = 0u;
    __syncthreads();
    #pragma unroll
    for (int t = 0; t < 3; ++t)
      if (vv[t] && (int)(vv[t] >> 11) == B1) atomicAdd(&s_h[vv[t] & 0x7FFu], 1u);
    __syncthreads();
    scanFind(MAXPER - NGT1);
    G = 0x3F000000u | ((unsigned)B1 << 11) | (unsigned)s_res[0];
  }
  if (tid == 0) gbits[b] = (int)G;
  if (tid < NCLS) {
    int f = 0;
    if (s_abs[tid] == CAP && !s_neg[tid]) {
      unsigned slast = __float_as_uint(
          keptScore[(size_t)b * NCLS * MAXPER + tid * MAXPER + (CAP - 1)]);
      if (slast >= G) f = 1;   // scores > 0.5: bit compare == float compare
    }
    flags[b * NCLS + tid] = f;
  }
}

// ---------------- K5: sort-based merge -> top-100 (rank-by-count) ----------------
// Rework of the largest measured kernel (15.7 us, round-6 amplify): 1024
// threads (8 stream slots/thread instead of 32 -> 4x shorter dependent phases,
// 16 waves of latency hiding) + prefix-scan pool gather (removes ~200
// serialized same-address LDS atomics). V-finding (two-level histogram) and all
// downstream logic are verbatim; pool slot order changes (thread-major vs
// atomic-arrival) which is output-invariant: rank-by-count sorts by key value
// and keys are unique.
__global__ __launch_bounds__(1024) void k_merge(const float* boxes, const float* keptScore,
                                                const int* keptRow, const int* kc, float* out) {
  int b = blockIdx.x;
  int tid = threadIdx.x;
  int wv = tid >> 6, lane = tid & 63;   // 16 waves
  __shared__ int s_kc[NCLS];
  __shared__ unsigned s_h[2048];
  __shared__ int s_wtot[16];
  __shared__ int s_res[2];
  __shared__ int s_sticky;
  __shared__ int s_navail;
  __shared__ unsigned long long s_pool[POOL];     // 2 KB
  __shared__ unsigned long long s_sorted[POOL];   // 2 KB

  if (tid < NCLS) s_kc[tid] = kc[b * NCLS + tid];
  if (tid == 0) { s_sticky = 0x7FFFFFFF; s_navail = 0; }
  if (tid < POOL) { s_pool[tid] = 0ull; s_sorted[tid] = 0ull; }
  s_h[tid] = 0u; s_h[tid + 1024] = 0u;
  __syncthreads();

  // load stream scores as w22 (8 per thread; invalid -> 0)
  unsigned sc[8];
  #pragma unroll
  for (int s = 0; s < 8; ++s) {
    int i = tid + s * 1024;
    unsigned vvv = 0u;
    if (i < NCLS * MAXPER) {
      int c = i / MAXPER, k = i - c * MAXPER;
      int kcv = s_kc[c];
      int ka = (kcv < 0) ? -kcv : kcv;
      if (k < ka)
        vvv = __float_as_uint(keptScore[(size_t)b * NCLS * MAXPER + i]) & 0x3FFFFFu;
    }
    sc[s] = vvv;
  }
  int live = 0;
  #pragma unroll
  for (int s = 0; s < 8; ++s) live += (sc[s] != 0u) ? 1 : 0;
  live = wave_red_sum_i32(live);
  if (lane == 0) s_wtot[wv] = live;
  #pragma unroll
  for (int s = 0; s < 8; ++s) if (sc[s]) atomicAdd(&s_h[sc[s] >> 11], 1u);
  __syncthreads();
  int T = 0;
  #pragma unroll
  for (int ww = 0; ww < 16; ++ww) T += s_wtot[ww];   // total stream entries

  // descending-order crossing over 2048 bins (2/thread, 16 waves) — select-style
  auto scanFind = [&](int target) {
    int b0 = 2047 - 2 * tid;
    int h0 = (int)s_h[b0];
    int h1 = (int)s_h[b0 - 1];
    int pair = h0 + h1;
    int incl = pair;
    #pragma unroll
    for (int o = 1; o < 64; o <<= 1) {
      int uu = __shfl_up(incl, o, 64);
      if (lane >= o) incl += uu;
    }
    if (lane == 63) s_wtot[wv] = incl;
    __syncthreads();
    int woff = 0;
    #pragma unroll
    for (int ww = 0; ww < 16; ++ww) woff += (ww < wv) ? s_wtot[ww] : 0;
    int excl = woff + incl - pair;
    if (excl < target && excl + h0 >= target) { s_res[0] = b0; s_res[1] = excl; }
    int e1 = excl + h0;
    if (e1 < target && e1 + h1 >= target) { s_res[0] = b0 - 1; s_res[1] = e1; }
    __syncthreads();
  };

  unsigned V = 1u;                     // all live if T <= 100
  if (T > MAXPER) {
    scanFind(MAXPER);
    int B1 = s_res[0], NGT1 = s_res[1];
    s_h[tid] = 0u; s_h[tid + 1024] = 0u;
    __syncthreads();
    #pragma unroll
    for (int s = 0; s < 8; ++s)
      if (sc[s] && (int)(sc[s] >> 11) == B1) atomicAdd(&s_h[sc[s] & 0x7FFu], 1u);
    __syncthreads();
    scanFind(MAXPER - NGT1);
    V = ((unsigned)B1 << 11) | (unsigned)s_res[0];   // count(>=V)>=100, count(>V)<100
  }

  // pool gather (>= V; V >= 1 excludes dead) via ONE block prefix-scan
  {
    int cg = 0;
    #pragma unroll
    for (int s = 0; s < 8; ++s) cg += (sc[s] >= V) ? 1 : 0;
    int incl = cg;
    #pragma unroll
    for (int o = 1; o < 64; o <<= 1) {
      int uu = __shfl_up(incl, o, 64);
      if (lane >= o) incl += uu;
    }
    if (lane == 63) s_wtot[wv] = incl;
    __syncthreads();
    int woff = 0;
    #pragma unroll
    for (int ww = 0; ww < 16; ++ww) woff += (ww < wv) ? s_wtot[ww] : 0;
    int pos = woff + incl - cg;
    #pragma unroll
    for (int s = 0; s < 8; ++s) {
      if (sc[s] >= V) {
        int i = tid + s * 1024;
        int c = i / MAXPER, k = i - c * MAXPER;
        int kcv = s_kc[c];
        int ka = (kcv < 0) ? -kcv : kcv;
        unsigned st = (kcv < 0 && k == ka - 1) ? 1u : 0u;
        unsigned row = (unsigned)keptRow[(size_t)b * NCLS * MAXPER + i];
        unsigned flat = row * 80u + (unsigned)c;
        if (pos < POOL)
          s_pool[pos] = ((unsigned long long)(0x3F000000u | sc[s]) << 32) |
                        (unsigned long long)(0x7FFFFFFFu - ((flat << 1) | st));
        ++pos;
      }
    }
  }
  __syncthreads();

  // rank-by-count (keys unique via flat index; zeros excluded -> ranks contiguous)
  if (tid < POOL) {
    unsigned long long mykey = s_pool[tid];
    if (mykey != 0ull) {
      int rank = 0;
      #pragma unroll 8
      for (int s = 0; s < POOL; ++s) rank += (s_pool[s] > mykey) ? 1 : 0;
      s_sorted[rank] = mykey;
    }
  }
  __syncthreads();

  if (tid < MAXPER) {
    unsigned long long key = s_sorted[tid];
    if (key != 0ull) {
      atomicAdd(&s_navail, 1);
      if ((((unsigned)key) & 1u) == 0u) atomicMin(&s_sticky, tid);  // low bit 0 <=> sticky
    }
  }
  __syncthreads();
  int navail = s_navail;
  int p = s_sticky;
  int n = (p < navail) ? MAXPER : navail;

  if (tid == 0) out[b] = (float)n;
  const int OB = BATCH;                    // 8
  const int OP = OB + BATCH * MAXPER * 4;  // 3208
  const int OS = OP + BATCH * MAXPER;      // 4008
  if (tid < MAXPER) {
    int k = tid;
    float bx0 = 0.f, bx1 = 0.f, bx2 = 0.f, bx3 = 0.f, scf = 0.f, cf = -1.0f;
    if (k < n) {
      int idx = (k > p) ? p : k;           // p == INT_MAX when no sticky -> idx = k
      unsigned long long key = s_sorted[idx];
      unsigned flat = (0x7FFFFFFFu - (unsigned)key) >> 1;
      unsigned cls = flat % 80u;
      unsigned row = flat / 80u;
      float4 bo = ((const float4*)boxes)[b * TOPK + row];
      bx0 = bo.x; bx1 = bo.y; bx2 = bo.z; bx3 = bo.w;
      scf = __uint_as_float((unsigned)(key >> 32));
      cf = (float)cls;
    }
    float* po = out + OB + (size_t)(b * MAXPER + k) * 4;
    po[0] = bx0; po[1] = bx1; po[2] = bx2; po[3] = bx3;
    out[OP + b * MAXPER + k] = scf;
    out[OS + b * MAXPER + k] = cf;
  }
}

extern "C" void kernel_launch(void* const* d_in, const int* in_sizes, int n_in,
                              void* d_out, int out_size, void* d_ws, size_t ws_size,
                              hipStream_t stream) {
  InPtrs P;
  for (int l = 0; l < 5; ++l) {
    P.cls[l]  = (const float*)d_in[4 * l + 0];
    P.bbox[l] = (const float*)d_in[4 * l + 1];
    P.shp[l]  = (const float*)d_in[4 * l + 2];
    P.loc[l]  = (const float*)d_in[4 * l + 3];
  }
  float* maxscore  = (float*)d_ws;                          // B*NA
  int*   sel       = (int*)(maxscore + BATCH * NA);         // B*TOPK
  float* boxes     = (float*)(sel + BATCH * TOPK);          // B*TOPK*4 (16B aligned)
  float* sv        = boxes + BATCH * TOPK * 4;              // B*80*TOPK (class-major)
  float* keptScore = sv + BATCH * NCLS * TOPK;              // B*80*100
  int*   keptRow   = (int*)(keptScore + BATCH * NCLS * MAXPER);
  int*   kc        = keptRow + BATCH * NCLS * MAXPER;
  int*   flags     = kc + BATCH * NCLS;
  int*   gbits     = flags + BATCH * NCLS;                  // per-batch G bit pattern
  float* out = (float*)d_out;

  k_maxscore<<<(BATCH * (NA / 4) * 4 + 255) / 256, 256, 0, stream>>>(P, maxscore);
  k_select<<<BATCH, 1024, 0, stream>>>(maxscore, sel);
  k_gather<<<BATCH * TOPK / 4, 256, 0, stream>>>(P, sel, boxes, sv);
  k_nms<<<BATCH * NCLS, 256, 0, stream>>>(boxes, sv, keptScore, keptRow, kc,
                                          (const int*)nullptr, (const int*)nullptr, CAP);
  k_cut<<<BATCH, 256, 0, stream>>>(keptScore, kc, flags, gbits);
  k_nms<<<BATCH * NCLS, 256, 0, stream>>>(boxes, sv, keptScore, keptRow, kc,
                                          flags, gbits, MAXPER);
  k_merge<<<BATCH, 1024, 0, stream>>>(boxes, keptScore, keptRow, kc, out);
}

// Round 11
// 187.009 us; speedup vs baseline: 3.1134x; 1.0010x over previous
//
#include <hip/hip_runtime.h>
#include <stdint.h>

#define NCLS 80
#define BATCH 8
#define NA 20460          // total anchors per image across 5 levels
#define TOPK 1000
#define MAXPER 100
#define CAP 8             // capped per-class NMS depth (exact fixup in pass 2)
#define POOL 256          // merge candidate pool (top-100 + tie slack)
#define IMG_WF 1280.0f
#define IMG_HF 768.0f
#define CLS_OFF 4096.0f
#define MAX_RATIO_ANCHOR 13.815510557964274f  // |log(1e-6)|
#define MAX_RATIO_BBOX   4.1351665567423557f  // |log(16/1000)|

// RN(a/b) > 0.5  <=>  a > b*(0.5 + 2^-25) as reals (0.5 mantissa even, tie->down).
// b has 24-bit mantissa, K2 has 25 -> product exact in f64; comparison exact.
#define K2_HALF_UP (0.5 + 0x1p-25)

__constant__ int   c_lvoff[6]  = {0, 15360, 19200, 20160, 20400, 20460};
__constant__ int   c_lvoff4[6] = {0, 3840, 4800, 5040, 5100, 5115};   // /4
__constant__ int   c_lw[5]    = {160, 80, 40, 20, 10};
__constant__ int   c_lh[5]    = {96, 48, 24, 12, 6};
__constant__ float c_ls[5]    = {8.f, 16.f, 32.f, 64.f, 128.f};

struct InPtrs {
  const float* cls[5];
  const float* bbox[5];
  const float* shp[5];
  const float* loc[5];
};

__device__ __forceinline__ float sigf(float x) { return 1.0f / (1.0f + expf(-x)); }

// ---- DPP wave64 reductions (VALU-only) ----
__device__ __forceinline__ int wave_red_sum_i32(int v) {
  int t;
  t = __builtin_amdgcn_update_dpp(0, v, 0x111, 0xf, 0xf, false); v += t;
  t = __builtin_amdgcn_update_dpp(0, v, 0x112, 0xf, 0xf, false); v += t;
  t = __builtin_amdgcn_update_dpp(0, v, 0x114, 0xf, 0xf, false); v += t;
  t = __builtin_amdgcn_update_dpp(0, v, 0x118, 0xf, 0xf, false); v += t;
  t = __builtin_amdgcn_update_dpp(0, v, 0x142, 0xf, 0xf, false); v += t;
  t = __builtin_amdgcn_update_dpp(0, v, 0x143, 0xf, 0xf, false); v += t;
  return __builtin_amdgcn_readlane(v, 63);
}
// top-2 of the wave's values: merge over disjoint sets; exact.
__device__ __forceinline__ void wave_red_top2(unsigned m1, unsigned m2,
                                              unsigned& r1, unsigned& r2) {
#define T2STEP(ctrl) { \
    unsigned o1 = (unsigned)__builtin_amdgcn_update_dpp(0, (int)m1, ctrl, 0xf, 0xf, false); \
    unsigned o2 = (unsigned)__builtin_amdgcn_update_dpp(0, (int)m2, ctrl, 0xf, 0xf, false); \
    unsigned tm = min(m1, o1); \
    m1 = max(m1, o1); \
    m2 = max(tm, max(m2, o2)); }
  T2STEP(0x111) T2STEP(0x112) T2STEP(0x114) T2STEP(0x118) T2STEP(0x142) T2STEP(0x143)
#undef T2STEP
  r1 = (unsigned)__builtin_amdgcn_readlane((int)m1, 63);
  r2 = (unsigned)__builtin_amdgcn_readlane((int)m2, 63);
}

// ---------------- K1: per-anchor max score, 4-way class split + shfl combine ----
// 640 blocks: lanes 4p..4p+3 each reduce 20 classes of anchor-quad p, combine
// via two xor-max steps (max is grouping-exact), lane h=0 applies loc mask +
// double sigmoid and writes. [round-8: 203.6 -> 194.7 with this k_maxscore]
__global__ __launch_bounds__(256) void k_maxscore(InPtrs P, float* maxscore) {
  int gid = blockIdx.x * 256 + threadIdx.x;
  int p = gid >> 2;                    // anchor-quad id
  int h = gid & 3;                     // class chunk: [20h, 20h+20)
  if (p >= BATCH * (NA / 4)) return;   // tail groups of 4 are wholly inactive
  int b = p / (NA / 4);
  int q = p - b * (NA / 4);            // float4 index within batch (level-merged)
  int l = 0;
  while (q >= c_lvoff4[l + 1]) ++l;
  int hw = c_lh[l] * c_lw[l];
  int sp = (q - c_lvoff4[l]) * 4;
  const float4* cls = (const float4*)(P.cls[l] + (size_t)(b * NCLS + h * 20) * hw + sp);
  int s4 = hw >> 2;                    // class stride in float4 units
  float4 m = cls[0];
  for (int c = 1; c < NCLS / 4; ++c) {
    float4 v = cls[(size_t)c * s4];
    m.x = fmaxf(m.x, v.x); m.y = fmaxf(m.y, v.y);
    m.z = fmaxf(m.z, v.z); m.w = fmaxf(m.w, v.w);
  }
  #pragma unroll
  for (int o = 1; o < 4; o <<= 1) {    // combine 4 chunks within the lane quad
    m.x = fmaxf(m.x, __shfl_xor(m.x, o, 64));
    m.y = fmaxf(m.y, __shfl_xor(m.y, o, 64));
    m.z = fmaxf(m.z, __shfl_xor(m.z, o, 64));
    m.w = fmaxf(m.w, __shfl_xor(m.w, o, 64));
  }
  if (h == 0) {
    float4 lo = *(const float4*)(P.loc[l] + (size_t)b * hw + sp);
    float4 r;
    r.x = (sigf(lo.x) >= 0.01f) ? sigf(sigf(m.x)) : 0.0f;  // monotone: max commutes
    r.y = (sigf(lo.y) >= 0.01f) ? sigf(sigf(m.y)) : 0.0f;
    r.z = (sigf(lo.z) >= 0.01f) ? sigf(sigf(m.z)) : 0.0f;
    r.w = (sigf(lo.w) >= 0.01f) ? sigf(sigf(m.w)) : 0.0f;
    ((float4*)maxscore)[(size_t)b * (NA / 4) + q] = r;
  }
}

// ---------------- K2: exact top-1000 per batch, in top_k order ----------------
// Two-level 2048-bucket LDS radix histogram + shfl suffix-scan (empirically the
// fastest variant). One-scan collect of >V, ==V fill ascending, hybrid bitonic.
__global__ __launch_bounds__(1024) void k_select(const float* maxscore, int* sel) {
  int b = blockIdx.x;
  const unsigned int* ms = (const unsigned int*)(maxscore + (size_t)b * NA);
  int tid = threadIdx.x;
  int wv = tid >> 6;
  int lane = tid & 63;
  __shared__ unsigned s_h[2048];      // level-1 then level-2 histogram (8 KB)
  __shared__ int s_wtot[16];
  __shared__ int s_res[2];            // {bucket, count-above} from scanFind
  __shared__ unsigned long long s_A[1024];
  __shared__ unsigned long long s_B[1024];

  // contiguous per-thread layout: thread t owns elements [20t, 20t+20)
  unsigned w[20];
  #pragma unroll
  for (int k = 0; k < 5; ++k) {
    int q = tid * 5 + k;
    uint4 u = (q < NA / 4) ? ((const uint4*)ms)[q] : make_uint4(0u, 0u, 0u, 0u);
    w[k * 4 + 0] = u.x & 0x3FFFFFu;
    w[k * 4 + 1] = u.y & 0x3FFFFFu;
    w[k * 4 + 2] = u.z & 0x3FFFFFu;
    w[k * 4 + 3] = u.w & 0x3FFFFFu;
  }
  int lim = NA - tid * 20;            // valid element count for this thread
  lim = (lim < 0) ? 0 : ((lim > 20) ? 20 : lim);

  s_h[tid] = 0u; s_h[tid + 1024] = 0u;
  __syncthreads();

  // descending-order crossing: unique bucket B with cntAbove(B) < target <= cntAbove(B)+h[B]
  auto scanFind = [&](int target) {
    int b0 = 2047 - 2 * tid;          // thread t owns descending positions 2t, 2t+1
    int h0 = (int)s_h[b0];
    int h1 = (int)s_h[b0 - 1];
    int pair = h0 + h1;
    int incl = pair;
    #pragma unroll
    for (int o = 1; o < 64; o <<= 1) {
      int uu = __shfl_up(incl, o, 64);
      if (lane >= o) incl += uu;
    }
    if (lane == 63) s_wtot[wv] = incl;
    __syncthreads();
    int woff = 0;
    #pragma unroll
    for (int ww = 0; ww < 16; ++ww) woff += (ww < wv) ? s_wtot[ww] : 0;
    int excl = woff + incl - pair;    // count in buckets strictly above b0
    if (excl < target && excl + h0 >= target) { s_res[0] = b0; s_res[1] = excl; }
    int e1 = excl + h0;
    if (e1 < target && e1 + h1 >= target) { s_res[0] = b0 - 1; s_res[1] = e1; }
    __syncthreads();
  };

  // ---- level 1: bucket = w >> 11 ----
  #pragma unroll
  for (int k = 0; k < 20; ++k) atomicAdd(&s_h[w[k] >> 11], 1u);
  __syncthreads();
  scanFind(TOPK);
  int B1 = s_res[0];
  int NGT1 = s_res[1];                // count of keys in buckets > B1 (< 1000)

  // ---- level 2: low 11 bits within bucket B1 ----
  s_h[tid] = 0u; s_h[tid + 1024] = 0u;
  __syncthreads();
  #pragma unroll
  for (int k = 0; k < 20; ++k)
    if ((int)(w[k] >> 11) == B1) atomicAdd(&s_h[w[k] & 0x7FFu], 1u);
  __syncthreads();
  scanFind(TOPK - NGT1);
  unsigned V = ((unsigned)B1 << 11) | (unsigned)s_res[0];  // exact 1000th key

  if (tid < 1024 - TOPK) s_A[TOPK + tid] = 0ull;  // pad slots (sink in desc sort)

  // ---- collect >V via ONE block prefix-scan (slot order arbitrary; bitonic sorts) ----
  int cgt = 0;
  #pragma unroll
  for (int k = 0; k < 20; ++k) cgt += (w[k] > V) ? 1 : 0;   // OOB w=0, never >V
  {
    int incl = cgt;
    #pragma unroll
    for (int o = 1; o < 64; o <<= 1) {
      int uu = __shfl_up(incl, o, 64);
      if (lane >= o) incl += uu;
    }
    if (lane == 63) s_wtot[wv] = incl;
    __syncthreads();
    int woff = 0, tot = 0;
    #pragma unroll
    for (int ww = 0; ww < 16; ++ww) { tot += s_wtot[ww]; woff += (ww < wv) ? s_wtot[ww] : 0; }
    int pos = woff + incl - cgt;
    #pragma unroll
    for (int k = 0; k < 20; ++k) {
      if (w[k] > V) {
        int i = tid * 20 + k;
        s_A[pos++] = ((unsigned long long)w[k] << 32) |
                     (unsigned long long)(0xFFFFFFFFu - (unsigned)i);
      }
    }
    int ngt = tot;
    int need = TOPK - ngt;            // >= 1; filled by ==V in ascending index order
    __syncthreads();                  // s_wtot reuse hazard fence

    // ---- ==V fill in ascending index order (from registers, contiguous layout) ----
    int ceq = 0;
    #pragma unroll
    for (int k = 0; k < 20; ++k) if (k < lim && w[k] == V) ++ceq;
    int incl2 = ceq;
    #pragma unroll
    for (int o = 1; o < 64; o <<= 1) {
      int uu = __shfl_up(incl2, o, 64);
      if (lane >= o) incl2 += uu;
    }
    if (lane == 63) s_wtot[wv] = incl2;
    __syncthreads();
    int woff2 = 0;
    #pragma unroll
    for (int ww = 0; ww < 16; ++ww) woff2 += (ww < wv) ? s_wtot[ww] : 0;
    int r = woff2 + incl2 - ceq;      // global exclusive prefix (index order)
    #pragma unroll
    for (int k = 0; k < 20; ++k) {
      if (k < lim && w[k] == V) {
        if (r < need) {
          int i = tid * 20 + k;
          s_A[ngt + r] = ((unsigned long long)V << 32) |
                         (unsigned long long)(0xFFFFFFFFu - (unsigned)i);
        }
        ++r;
      }
    }
  }
  __syncthreads();

  // hybrid bitonic sort, descending, one key/thread in registers.
  unsigned long long key = s_A[tid];
  int tog = 0;   // 0 -> s_B first (s_A holds live data at entry)
  for (unsigned k = 2; k <= 1024; k <<= 1) {
    for (unsigned j = k >> 1; j > 0; j >>= 1) {
      unsigned long long other;
      if (j >= 64) {
        unsigned long long* cur = tog ? s_A : s_B;
        cur[tid] = key;
        __syncthreads();
        other = cur[tid ^ (int)j];
        tog ^= 1;
      } else {
        other = __shfl_xor(key, (int)j, 64);
      }
      bool takeMax = (((tid & (int)k) == 0) == ((tid & (int)j) == 0));
      unsigned long long mx = (key > other) ? key : other;
      unsigned long long mn = (key > other) ? other : key;
      key = takeMax ? mx : mn;
    }
  }
  if (tid < TOPK) {
    sel[b * TOPK + tid] = (int)(0xFFFFFFFFu - (unsigned)(key & 0xFFFFFFFFull));
  }
}

// ---------------- K3: decode boxes + 80 class scores, one WAVE per row ----------
__global__ __launch_bounds__(256) void k_gather(InPtrs P, const int* sel, float* boxes, float* sv) {
  int wvi = threadIdx.x >> 6;
  int lane = threadIdx.x & 63;
  int wid = blockIdx.x * 4 + wvi;      // grid is exactly BATCH*TOPK/4 blocks
  int b = wid / TOPK;
  int r = wid - b * TOPK;
  __shared__ float s_sc[4][NCLS];

  int a = sel[b * TOPK + r];       // uniform -> broadcast load
  int l = 0;
  while (a >= c_lvoff[l + 1]) ++l;
  int within = a - c_lvoff[l];
  int W = c_lw[l], H = c_lh[l];
  int y = within / W, x = within - y * W;
  int hw = H * W;
  int sp = within;
  float stride = c_ls[l];
  float px = (float)x * stride;
  float py = (float)y * stride;
  float pw = 4.0f * stride;

  const float* shp = P.shp[l];
  float dws = shp[(b * 2 + 0) * hw + sp];
  float dhs = shp[(b * 2 + 1) * hw + sp];
  dws = fminf(fmaxf(dws, -MAX_RATIO_ANCHOR), MAX_RATIO_ANCHOR);
  dhs = fminf(fmaxf(dhs, -MAX_RATIO_ANCHOR), MAX_RATIO_ANCHOR);
  float gw = pw * expf(dws);
  float gh = pw * expf(dhs);
  float ax1 = px - 0.5f * gw, ax2 = px + 0.5f * gw;
  float ay1 = py - 0.5f * gh, ay2 = py + 0.5f * gh;

  const float* bb = P.bbox[l];
  float dx = bb[(b * 4 + 0) * hw + sp];
  float dy = bb[(b * 4 + 1) * hw + sp];
  float dw = bb[(b * 4 + 2) * hw + sp];
  float dh = bb[(b * 4 + 3) * hw + sp];
  dw = fminf(fmaxf(dw, -MAX_RATIO_BBOX), MAX_RATIO_BBOX);
  dh = fminf(fmaxf(dh, -MAX_RATIO_BBOX), MAX_RATIO_BBOX);
  float px2 = (ax1 + ax2) * 0.5f, py2 = (ay1 + ay2) * 0.5f;
  float pw2 = ax2 - ax1, ph2 = ay2 - ay1;
  float gx = px2 + pw2 * dx, gy = py2 + ph2 * dy;
  float gw2 = pw2 * expf(dw), gh2 = ph2 * expf(dh);
  float x1 = fminf(fmaxf(gx - 0.5f * gw2, 0.0f), IMG_WF);
  float x2 = fminf(fmaxf(gx + 0.5f * gw2, 0.0f), IMG_WF);
  float y1 = fminf(fmaxf(gy - 0.5f * gh2, 0.0f), IMG_HF);
  float y2 = fminf(fmaxf(gy + 0.5f * gh2, 0.0f), IMG_HF);
  if (lane == 0) {
    float4 st; st.x = x1; st.y = y1; st.z = x2; st.w = y2;
    ((float4*)boxes)[b * TOPK + r] = st;
  }

  const float* cls = P.cls[l];
  float sl = sigf(P.loc[l][b * hw + sp]);
  bool mask = (sl >= 0.01f);
  int base = (b * NCLS) * hw + sp;
  for (int c = lane; c < NCLS; c += 64) {
    float vv = 0.0f;
    if (mask) {
      float s2 = sigf(sigf(cls[base + c * hw]));
      vv = (s2 > 0.05f) ? s2 : 0.0f;   // SCORE_THR (strict >)
    }
    s_sc[wvi][c] = vv;
  }
  __syncthreads();
  int t = threadIdx.x;
  if (t < NCLS) {
    int r0 = blockIdx.x * 4 - b * TOPK;   // row of wave 0 (TOPK % 4 == 0)
    float4 o; o.x = s_sc[0][t]; o.y = s_sc[1][t]; o.z = s_sc[2][t]; o.w = s_sc[3][t];
    *(float4*)(sv + ((size_t)(b * NCLS + t) * TOPK + r0)) = o;
  }
}

// ---------------- K4: per-(batch,class) greedy NMS, FOUR waves, TWO picks/round --
// fixup != 0 (pass 2): the k_cut launch is FUSED into this kernel's head — each
// block recomputes the per-batch G (100th-largest of the capped union) and its
// own flag decision from (kc, keptScore). Inputs and arithmetic are identical to
// the old k_cut, so every block of batch b derives the same G / flag bit-exactly;
// unflagged blocks early-exit. Removes one launch + the flags/gbits round-trip.
__global__ __launch_bounds__(256) void k_nms(const float* boxes, const float* sv,
                                             float* keptScore, int* keptRow, int* kc,
                                             int fixup, int cap) {
  int bc = blockIdx.x;              // 0..639
  int b = bc / NCLS;
  int c = bc - b * NCLS;
  int tid = threadIdx.x;
  int wv = tid >> 6, lane = tid & 63;

  __shared__ float4 s_box[TOPK];            // 16 KB (offset coords)
  __shared__ float  s_ard[TOPK];            // 4 KB: |val| = area, sign = degenerate
  __shared__ unsigned long long s_p2[2][4]; // parity-buffered per-wave (top1,top2)
  __shared__ int s_abs[NCLS];
  __shared__ int s_neg[NCLS];
  __shared__ unsigned s_h[2048];            // 8 KB (fixup G-histogram)
  __shared__ int s_wtot[4];
  __shared__ int s_res[2];
  __shared__ int s_tot[4];

  unsigned Glow = 0u;               // low-22 score bits of G; 0 -> no truncation
  if (fixup) {
    // ---- inline k_cut: compute G(b) and this class's flag ----
    if (tid < NCLS) {
      int v = kc[b * NCLS + tid];
      s_abs[tid] = (v < 0) ? -v : v;
      s_neg[tid] = (v < 0) ? 1 : 0;
    }
    #pragma unroll
    for (int j = 0; j < 8; ++j) s_h[tid * 8 + j] = 0u;
    __syncthreads();

    unsigned vv[3] = {0u, 0u, 0u};
    #pragma unroll
    for (int t = 0; t < 3; ++t) {
      int e = tid + t * 256;
      if (e < NCLS * CAP) {
        int cc = e / CAP, k = e - cc * CAP;
        if (k < s_abs[cc])
          vv[t] = __float_as_uint(keptScore[(size_t)b * NCLS * MAXPER + cc * MAXPER + k])
                  & 0x3FFFFFu;
      }
    }
    int live = ((vv[0] != 0u) ? 1 : 0) + ((vv[1] != 0u) ? 1 : 0) + ((vv[2] != 0u) ? 1 : 0);
    live = wave_red_sum_i32(live);
    if (lane == 0) s_tot[wv] = live;
    #pragma unroll
    for (int t = 0; t < 3; ++t) if (vv[t]) atomicAdd(&s_h[vv[t] >> 11], 1u);
    __syncthreads();
    int T = s_tot[0] + s_tot[1] + s_tot[2] + s_tot[3];

    auto scanFind = [&](int target) {
      int base = 2047 - 8 * tid;
      int h[8]; int loc = 0;
      #pragma unroll
      for (int j = 0; j < 8; ++j) { h[j] = (int)s_h[base - j]; loc += h[j]; }
      int incl = loc;
      #pragma unroll
      for (int o = 1; o < 64; o <<= 1) {
        int uu = __shfl_up(incl, o, 64);
        if (lane >= o) incl += uu;
      }
      if (lane == 63) s_wtot[wv] = incl;
      __syncthreads();
      int woff = 0;
      #pragma unroll
      for (int ww = 0; ww < 4; ++ww) woff += (ww < wv) ? s_wtot[ww] : 0;
      int e = woff + incl - loc;
      #pragma unroll
      for (int j = 0; j < 8; ++j) {
        if (e < target && e + h[j] >= target) { s_res[0] = base - j; s_res[1] = e; }
        e += h[j];
      }
      __syncthreads();
    };

    unsigned G = 0u;
    if (T >= MAXPER) {
      scanFind(MAXPER);
      int B1 = s_res[0], NGT1 = s_res[1];
      #pragma unroll
      for (int j = 0; j < 8; ++j) s_h[tid * 8 + j] = 0u;
      __syncthreads();
      #pragma unroll
      for (int t = 0; t < 3; ++t)
        if (vv[t] && (int)(vv[t] >> 11) == B1) atomicAdd(&s_h[vv[t] & 0x7FFu], 1u);
      __syncthreads();
      scanFind(MAXPER - NGT1);
      G = 0x3F000000u | ((unsigned)B1 << 11) | (unsigned)s_res[0];
    }
    // flag for THIS class (identical condition to old k_cut):
    int run = 0;
    if (s_abs[c] == CAP && !s_neg[c]) {
      unsigned slast = __float_as_uint(
          keptScore[(size_t)b * NCLS * MAXPER + c * MAXPER + (CAP - 1)]);
      if (slast >= G) run = 1;   // scores > 0.5: bit compare == float compare
    }
    if (!run) return;            // uniform early-exit
    Glow = G & 0x3FFFFFu;
  }

  float x1[4], y1[4], x2[4], y2[4], ar[4];
  unsigned key[4];
  float off = (float)c * CLS_OFF;   // exact in f32
  const float* svc = sv + (size_t)(b * NCLS + c) * TOPK;   // class-major: contiguous
  #pragma unroll
  for (int j = 0; j < 4; ++j) {
    int row = j * 256 + tid;
    if (row < TOPK) {
      float4 bo = ((const float4*)boxes)[b * TOPK + row];
      float a = bo.x + off, d = bo.y + off, e = bo.z + off, f = bo.w + off;
      x1[j] = a; y1[j] = d; x2[j] = e; y2[j] = f;
      ar[j] = (e - a) * (f - d);
      unsigned bits = __float_as_uint(svc[row]);   // 0 or in [0x3F000001,0x3F3C0000)
      key[j] = ((bits & 0x3FFFFFu) << 10) | (1023u - (unsigned)row);
      float sden = ar[j] + 1e-6f;
      bool deg = !((double)ar[j] > (double)sden * K2_HALF_UP);
      float4 sb; sb.x = a; sb.y = d; sb.z = e; sb.w = f;
      s_box[row] = sb;
      s_ard[row] = __uint_as_float(__float_as_uint(ar[j]) | (deg ? 0x80000000u : 0u));
    } else {
      x1[j] = y1[j] = x2[j] = y2[j] = ar[j] = 0.0f;
      key[j] = 0u;
    }
  }
  __syncthreads();   // boxes visible

  int kept = 0;
  bool sticky = false;
  float* ks = keptScore + (size_t)(b * NCLS + c) * MAXPER;
  int*   kr = keptRow   + (size_t)(b * NCLS + c) * MAXPER;

  for (int round = 0; round < cap; ++round) {
    int par = round & 1;
    unsigned hi1 = max(key[0], key[1]), lo1 = min(key[0], key[1]);
    unsigned hi2 = max(key[2], key[3]), lo2 = min(key[2], key[3]);
    unsigned m1 = max(hi1, hi2);
    unsigned m2 = max(min(hi1, hi2), max(lo1, lo2));
    unsigned w1, w2;
    wave_red_top2(m1, m2, w1, w2);
    if (lane == 0) s_p2[par][wv] = ((unsigned long long)w1 << 32) | w2;
    __syncthreads();                          // ONE barrier per round
    unsigned k0 = 0u, k1 = 0u;
    #pragma unroll
    for (int w = 0; w < 4; ++w) {
      unsigned long long pp = s_p2[par][w];
      unsigned p1 = (unsigned)(pp >> 32), p2 = (unsigned)pp;
      unsigned tm = min(k0, p1);
      k0 = max(k0, p1);
      k1 = max(tm, max(k1, p2));
    }
    if (k0 < 1024u) break;                    // no live entries
    if ((k0 >> 10) < Glow) break;             // rest of stream < G: outside top-100
    // ---- pick a1 ----
    int brow1 = 1023 - (int)(k0 & 1023u);
    float bs1 = __uint_as_float(0x3F000000u | (k0 >> 10));
    float4 bb1 = s_box[brow1];
    unsigned au1 = __float_as_uint(s_ard[brow1]);
    bool deg1 = (au1 >> 31) != 0u;
    float ba1 = __uint_as_float(au1 & 0x7FFFFFFFu);
    if (tid == 0) { ks[kept] = bs1; kr[kept] = brow1; }
    kept++;
    if (deg1) { sticky = true; break; }       // repeats forever in the ref scan
    if (kept >= cap) break;
    bool live2 = (k1 >= 1024u) && ((k1 >> 10) >= Glow);
    if (!live2) break;
    // ---- try pick a2 (pre-suppression 2nd max) ----
    bool do2 = false, deg2 = false;
    float4 bb2; float ba2 = 0.0f;
    {
      int brow2 = 1023 - (int)(k1 & 1023u);
      float bs2 = __uint_as_float(0x3F000000u | (k1 >> 10));
      bb2 = s_box[brow2];
      unsigned au2 = __float_as_uint(s_ard[brow2]);
      deg2 = (au2 >> 31) != 0u;
      ba2 = __uint_as_float(au2 & 0x7FFFFFFFu);
      float ltx = fmaxf(bb1.x, bb2.x), rbx = fminf(bb1.z, bb2.z);
      float lty = fmaxf(bb1.y, bb2.y), rby = fminf(bb1.w, bb2.w);
      float w_ = fmaxf(rbx - ltx, 0.0f), h_ = fmaxf(rby - lty, 0.0f);
      float inter = w_ * h_;
      float denom = ((ba1 + ba2) - inter) + 1e-6f;
      if (!((double)inter > (double)denom * K2_HALF_UP)) {
        do2 = true;
        if (tid == 0) { ks[kept] = bs2; kr[kept] = brow2; }
        kept++;
      }
    }
    if (do2 && deg2) { sticky = true; break; }
    // ---- suppression: each box vs a1 (and a2 if emitted); OR == sequential ----
    #pragma unroll
    for (int j = 0; j < 4; ++j) {
      {
        float ltx = fmaxf(bb1.x, x1[j]), rbx = fminf(bb1.z, x2[j]);
        float lty = fmaxf(bb1.y, y1[j]), rby = fminf(bb1.w, y2[j]);
        float w_ = fmaxf(rbx - ltx, 0.0f), h_ = fmaxf(rby - lty, 0.0f);
        float inter = w_ * h_;
        float denom = ((ba1 + ar[j]) - inter) + 1e-6f;
        if ((double)inter > (double)denom * K2_HALF_UP) key[j] = 0u;
      }
      if (do2) {
        float ltx = fmaxf(bb2.x, x1[j]), rbx = fminf(bb2.z, x2[j]);
        float lty = fmaxf(bb2.y, y1[j]), rby = fminf(bb2.w, y2[j]);
        float w_ = fmaxf(rbx - ltx, 0.0f), h_ = fmaxf(rby - lty, 0.0f);
        float inter = w_ * h_;
        float denom = ((ba2 + ar[j]) - inter) + 1e-6f;
        if ((double)inter > (double)denom * K2_HALF_UP) key[j] = 0u;
      }
    }
    if (kept >= cap) break;
  }
  if (tid == 0) kc[b * NCLS + c] = sticky ? -kept : kept;
}

// ---------------- K5: sort-based merge -> top-100 (rank-by-count) ----------------
// 1024 threads (8 stream slots/thread -> short dependent phases, 16 waves of
// latency hiding) + prefix-scan pool gather. [round-10: 194.7 -> 187.2]
__global__ __launch_bounds__(1024) void k_merge(const float* boxes, const float* keptScore,
                                                const int* keptRow, const int* kc, float* out) {
  int b = blockIdx.x;
  int tid = threadIdx.x;
  int wv = tid >> 6, lane = tid & 63;   // 16 waves
  __shared__ int s_kc[NCLS];
  __shared__ unsigned s_h[2048];
  __shared__ int s_wtot[16];
  __shared__ int s_res[2];
  __shared__ int s_sticky;
  __shared__ int s_navail;
  __shared__ unsigned long long s_pool[POOL];     // 2 KB
  __shared__ unsigned long long s_sorted[POOL];   // 2 KB

  if (tid < NCLS) s_kc[tid] = kc[b * NCLS + tid];
  if (tid == 0) { s_sticky = 0x7FFFFFFF; s_navail = 0; }
  if (tid < POOL) { s_pool[tid] = 0ull; s_sorted[tid] = 0ull; }
  s_h[tid] = 0u; s_h[tid + 1024] = 0u;
  __syncthreads();

  // load stream scores as w22 (8 per thread; invalid -> 0)
  unsigned sc[8];
  #pragma unroll
  for (int s = 0; s < 8; ++s) {
    int i = tid + s * 1024;
    unsigned vvv = 0u;
    if (i < NCLS * MAXPER) {
      int c = i / MAXPER, k = i - c * MAXPER;
      int kcv = s_kc[c];
      int ka = (kcv < 0) ? -kcv : kcv;
      if (k < ka)
        vvv = __float_as_uint(keptScore[(size_t)b * NCLS * MAXPER + i]) & 0x3FFFFFu;
    }
    sc[s] = vvv;
  }
  int live = 0;
  #pragma unroll
  for (int s = 0; s < 8; ++s) live += (sc[s] != 0u) ? 1 : 0;
  live = wave_red_sum_i32(live);
  if (lane == 0) s_wtot[wv] = live;
  #pragma unroll
  for (int s = 0; s < 8; ++s) if (sc[s]) atomicAdd(&s_h[sc[s] >> 11], 1u);
  __syncthreads();
  int T = 0;
  #pragma unroll
  for (int ww = 0; ww < 16; ++ww) T += s_wtot[ww];   // total stream entries

  // descending-order crossing over 2048 bins (2/thread, 16 waves)
  auto scanFind = [&](int target) {
    int b0 = 2047 - 2 * tid;
    int h0 = (int)s_h[b0];
    int h1 = (int)s_h[b0 - 1];
    int pair = h0 + h1;
    int incl = pair;
    #pragma unroll
    for (int o = 1; o < 64; o <<= 1) {
      int uu = __shfl_up(incl, o, 64);
      if (lane >= o) incl += uu;
    }
    if (lane == 63) s_wtot[wv] = incl;
    __syncthreads();
    int woff = 0;
    #pragma unroll
    for (int ww = 0; ww < 16; ++ww) woff += (ww < wv) ? s_wtot[ww] : 0;
    int excl = woff + incl - pair;
    if (excl < target && excl + h0 >= target) { s_res[0] = b0; s_res[1] = excl; }
    int e1 = excl + h0;
    if (e1 < target && e1 + h1 >= target) { s_res[0] = b0 - 1; s_res[1] = e1; }
    __syncthreads();
  };

  unsigned V = 1u;                     // all live if T <= 100
  if (T > MAXPER) {
    scanFind(MAXPER);
    int B1 = s_res[0], NGT1 = s_res[1];
    s_h[tid] = 0u; s_h[tid + 1024] = 0u;
    __syncthreads();
    #pragma unroll
    for (int s = 0; s < 8; ++s)
      if (sc[s] && (int)(sc[s] >> 11) == B1) atomicAdd(&s_h[sc[s] & 0x7FFu], 1u);
    __syncthreads();
    scanFind(MAXPER - NGT1);
    V = ((unsigned)B1 << 11) | (unsigned)s_res[0];   // count(>=V)>=100, count(>V)<100
  }

  // pool gather (>= V; V >= 1 excludes dead) via ONE block prefix-scan
  {
    int cg = 0;
    #pragma unroll
    for (int s = 0; s < 8; ++s) cg += (sc[s] >= V) ? 1 : 0;
    int incl = cg;
    #pragma unroll
    for (int o = 1; o < 64; o <<= 1) {
      int uu = __shfl_up(incl, o, 64);
      if (lane >= o) incl += uu;
    }
    if (lane == 63) s_wtot[wv] = incl;
    __syncthreads();
    int woff = 0;
    #pragma unroll
    for (int ww = 0; ww < 16; ++ww) woff += (ww < wv) ? s_wtot[ww] : 0;
    int pos = woff + incl - cg;
    #pragma unroll
    for (int s = 0; s < 8; ++s) {
      if (sc[s] >= V) {
        int i = tid + s * 1024;
        int c = i / MAXPER, k = i - c * MAXPER;
        int kcv = s_kc[c];
        int ka = (kcv < 0) ? -kcv : kcv;
        unsigned st = (kcv < 0 && k == ka - 1) ? 1u : 0u;
        unsigned row = (unsigned)keptRow[(size_t)b * NCLS * MAXPER + i];
        unsigned flat = row * 80u + (unsigned)c;
        if (pos < POOL)
          s_pool[pos] = ((unsigned long long)(0x3F000000u | sc[s]) << 32) |
                        (unsigned long long)(0x7FFFFFFFu - ((flat << 1) | st));
        ++pos;
      }
    }
  }
  __syncthreads();

  // rank-by-count (keys unique via flat index; zeros excluded -> ranks contiguous)
  if (tid < POOL) {
    unsigned long long mykey = s_pool[tid];
    if (mykey != 0ull) {
      int rank = 0;
      #pragma unroll 8
      for (int s = 0; s < POOL; ++s) rank += (s_pool[s] > mykey) ? 1 : 0;
      s_sorted[rank] = mykey;
    }
  }
  __syncthreads();

  if (tid < MAXPER) {
    unsigned long long key = s_sorted[tid];
    if (key != 0ull) {
      atomicAdd(&s_navail, 1);
      if ((((unsigned)key) & 1u) == 0u) atomicMin(&s_sticky, tid);  // low bit 0 <=> sticky
    }
  }
  __syncthreads();
  int navail = s_navail;
  int p = s_sticky;
  int n = (p < navail) ? MAXPER : navail;

  if (tid == 0) out[b] = (float)n;
  const int OB = BATCH;                    // 8
  const int OP = OB + BATCH * MAXPER * 4;  // 3208
  const int OS = OP + BATCH * MAXPER;      // 4008
  if (tid < MAXPER) {
    int k = tid;
    float bx0 = 0.f, bx1 = 0.f, bx2 = 0.f, bx3 = 0.f, scf = 0.f, cf = -1.0f;
    if (k < n) {
      int idx = (k > p) ? p : k;           // p == INT_MAX when no sticky -> idx = k
      unsigned long long key = s_sorted[idx];
      unsigned flat = (0x7FFFFFFFu - (unsigned)key) >> 1;
      unsigned cls = flat % 80u;
      unsigned row = flat / 80u;
      float4 bo = ((const float4*)boxes)[b * TOPK + row];
      bx0 = bo.x; bx1 = bo.y; bx2 = bo.z; bx3 = bo.w;
      scf = __uint_as_float((unsigned)(key >> 32));
      cf = (float)cls;
    }
    float* po = out + OB + (size_t)(b * MAXPER + k) * 4;
    po[0] = bx0; po[1] = bx1; po[2] = bx2; po[3] = bx3;
    out[OP + b * MAXPER + k] = scf;
    out[OS + b * MAXPER + k] = cf;
  }
}

extern "C" void kernel_launch(void* const* d_in, const int* in_sizes, int n_in,
                              void* d_out, int out_size, void* d_ws, size_t ws_size,
                              hipStream_t stream) {
  InPtrs P;
  for (int l = 0; l < 5; ++l) {
    P.cls[l]  = (const float*)d_in[4 * l + 0];
    P.bbox[l] = (const float*)d_in[4 * l + 1];
    P.shp[l]  = (const float*)d_in[4 * l + 2];
    P.loc[l]  = (const float*)d_in[4 * l + 3];
  }
  float* maxscore  = (float*)d_ws;                          // B*NA
  int*   sel       = (int*)(maxscore + BATCH * NA);         // B*TOPK
  float* boxes     = (float*)(sel + BATCH * TOPK);          // B*TOPK*4 (16B aligned)
  float* sv        = boxes + BATCH * TOPK * 4;              // B*80*TOPK (class-major)
  float* keptScore = sv + BATCH * NCLS * TOPK;              // B*80*100
  int*   keptRow   = (int*)(keptScore + BATCH * NCLS * MAXPER);
  int*   kc        = keptRow + BATCH * NCLS * MAXPER;
  float* out = (float*)d_out;

  k_maxscore<<<(BATCH * (NA / 4) * 4 + 255) / 256, 256, 0, stream>>>(P, maxscore);
  k_select<<<BATCH, 1024, 0, stream>>>(maxscore, sel);
  k_gather<<<BATCH * TOPK / 4, 256, 0, stream>>>(P, sel, boxes, sv);
  k_nms<<<BATCH * NCLS, 256, 0, stream>>>(boxes, sv, keptScore, keptRow, kc, 0, CAP);
  k_nms<<<BATCH * NCLS, 256, 0, stream>>>(boxes, sv, keptScore, keptRow, kc, 1, MAXPER);
  k_merge<<<BATCH, 1024, 0, stream>>>(boxes, keptScore, keptRow, kc, out);
}